// Round 1
// baseline (4202.576 us; speedup 1.0000x reference)
//
#include <hip/hip_runtime.h>
#include <math.h>

#define N_NODES 10000
#define ND 64
#define H 128
#define LAYERS 4
#define KNN 16
#define TD 16
#define E_EDGES (N_NODES * KNN)

__device__ __forceinline__ float silu(float x) { return x / (1.0f + __expf(-x)); }

// ---------------------------------------------------------------------------
// KNN: one thread per query node; all positions (+sq) staged in LDS as float4.
// d2 = sq_i + sq_j - 2*dot (reference formula); strict < keeps earliest index
// on ties (matches lax.top_k lowest-index-wins).
// ---------------------------------------------------------------------------
__global__ __launch_bounds__(256) void knn_kernel(const float* __restrict__ pos,
                                                  int* __restrict__ nbr) {
  __shared__ float4 P[N_NODES];  // 160000 bytes
  int tid = threadIdx.x;
  for (int j = tid; j < N_NODES; j += 256) {
    float x = pos[j * 3 + 0], y = pos[j * 3 + 1], z = pos[j * 3 + 2];
    P[j] = make_float4(x, y, z, x * x + y * y + z * z);
  }
  __syncthreads();
  int i = blockIdx.x * 256 + tid;
  if (i >= N_NODES) return;
  float4 q = P[i];
  float bd[KNN];
  int bi[KNN];
#pragma unroll
  for (int k = 0; k < KNN; ++k) { bd[k] = __builtin_inff(); bi[k] = 0; }
#pragma unroll 4
  for (int j = 0; j < N_NODES; ++j) {
    float4 p = P[j];
    float d2 = q.w + p.w - 2.0f * (q.x * p.x + q.y * p.y + q.z * p.z);
    if (j == i) d2 = __builtin_inff();
    if (d2 < bd[KNN - 1]) {
      // branch-free sorted insert, static indices only
#pragma unroll
      for (int k = KNN - 1; k >= 1; --k) {
        bool stay = (bd[k] <= d2);
        bool here = (bd[k - 1] <= d2);
        float nd = stay ? bd[k] : (here ? d2 : bd[k - 1]);
        int ni = stay ? bi[k] : (here ? j : bi[k - 1]);
        bd[k] = nd;
        bi[k] = ni;
      }
      if (bd[0] > d2) { bd[0] = d2; bi[0] = j; }
    }
  }
#pragma unroll
  for (int k = 0; k < KNN; ++k) nbr[i * KNN + k] = bi[k];
}

// ---------------------------------------------------------------------------
// CSR build (deterministic): count -> scan -> scatter -> per-node sort
// ---------------------------------------------------------------------------
__global__ void deg_count_kernel(const int* __restrict__ nbr, int* __restrict__ degi) {
  int e = blockIdx.x * 256 + threadIdx.x;
  if (e < E_EDGES) atomicAdd(&degi[nbr[e]], 1);
}

__global__ __launch_bounds__(1024) void scan_kernel(const int* __restrict__ degi,
                                                    int* __restrict__ off,
                                                    int* __restrict__ cursor) {
  __shared__ int part[1024];
  int t = threadIdx.x;
  int base = t * 10;
  int sum = 0;
  if (t < 1000)
    for (int i = 0; i < 10; ++i) sum += degi[base + i];
  part[t] = sum;
  __syncthreads();
  for (int stp = 1; stp < 1024; stp <<= 1) {
    int v = (t >= stp) ? part[t - stp] : 0;
    __syncthreads();
    part[t] += v;
    __syncthreads();
  }
  if (t < 1000) {
    int run = (t == 0) ? 0 : part[t - 1];
    for (int i = 0; i < 10; ++i) {
      off[base + i] = run;
      cursor[base + i] = run;
      run += degi[base + i];
    }
  }
  if (t == 0) off[N_NODES] = E_EDGES;
}

__global__ void scatter_kernel(const int* __restrict__ nbr, int* __restrict__ cursor,
                               int* __restrict__ eid) {
  int e = blockIdx.x * 256 + threadIdx.x;
  if (e < E_EDGES) {
    int d = nbr[e];
    int p = atomicAdd(&cursor[d], 1);
    eid[p] = e;
  }
}

__global__ void sort_kernel(const int* __restrict__ off, int* __restrict__ eid) {
  int n = blockIdx.x * 256 + threadIdx.x;
  if (n >= N_NODES) return;
  int a = off[n], b = off[n + 1];
  for (int i = a + 1; i < b; ++i) {
    int v = eid[i];
    int j = i - 1;
    while (j >= a && eid[j] > v) { eid[j + 1] = eid[j]; --j; }
    eid[j + 1] = v;
  }
}

// ---------------------------------------------------------------------------
// Input projection: h0 = concat(x, s, temb) @ proj_w + proj_b. 2 nodes/block.
// ---------------------------------------------------------------------------
__global__ __launch_bounds__(256) void proj_kernel(const float* __restrict__ x,
                                                   const float* __restrict__ s,
                                                   const float* __restrict__ tptr,
                                                   const float* __restrict__ pw,
                                                   const float* __restrict__ pb,
                                                   float* __restrict__ h) {
  __shared__ float inp[2][81];
  int tid = threadIdx.x;
  int g = tid >> 7;
  int o = tid & 127;
  int node = blockIdx.x * 2 + g;
  float t = tptr[0];
  if (o < 64) inp[g][o] = x[node * ND + o];
  else if (o == 64) inp[g][64] = s[node];
  else if (o < 81) {
    int j = o - 65;
    int jj = (j < 8) ? j : (j - 8);
    float f = __expf(-4.0f * (float)jj / 7.0f);
    float a = t * f;
    inp[g][o] = (j < 8) ? sinf(a) : cosf(a);
  }
  __syncthreads();
  float acc = pb[o];
#pragma unroll
  for (int c = 0; c < 81; ++c) acc = fmaf(inp[g][c], pw[c * H + o], acc);
  h[node * H + o] = acc;
}

// ---------------------------------------------------------------------------
// A = h @ ew1[0:128] + eb1 ; B = h @ ew1[128:256].  16 nodes per block.
// ---------------------------------------------------------------------------
__global__ __launch_bounds__(256) void ab_kernel(const float* __restrict__ h,
                                                 const float* __restrict__ ew1,
                                                 const float* __restrict__ eb1,
                                                 float* __restrict__ A,
                                                 float* __restrict__ B) {
  __shared__ float hs[16][H];
  int tid = threadIdx.x;
  int n0 = blockIdx.x * 16;
  for (int idx = tid; idx < 16 * H; idx += 256) {
    int n = idx >> 7, c = idx & 127;
    hs[n][c] = h[(n0 + n) * H + c];
  }
  __syncthreads();
  int part = tid >> 7, o = tid & 127;
  const float* W = ew1 + part * H * H;
  float acc[16];
#pragma unroll
  for (int n = 0; n < 16; ++n) acc[n] = 0.0f;
  for (int c = 0; c < H; c += 4) {
    float4 wv;
    wv.x = W[(c + 0) * H + o];
    wv.y = W[(c + 1) * H + o];
    wv.z = W[(c + 2) * H + o];
    wv.w = W[(c + 3) * H + o];
#pragma unroll
    for (int n = 0; n < 16; ++n) {
      float4 hv = *(const float4*)&hs[n][c];
      acc[n] = fmaf(hv.x, wv.x, acc[n]);
      acc[n] = fmaf(hv.y, wv.y, acc[n]);
      acc[n] = fmaf(hv.z, wv.z, acc[n]);
      acc[n] = fmaf(hv.w, wv.w, acc[n]);
    }
  }
  float bias = (part == 0) ? eb1[o] : 0.0f;
  float* out = (part == 0) ? A : B;
#pragma unroll
  for (int n = 0; n < 16; ++n) out[(n0 + n) * H + o] = acc[n] + bias;
}

// ---------------------------------------------------------------------------
// Fused edge message + aggregation. 4 dst nodes per block; 16-edge groups.
// pre = A[dst] + B[src] + r2*w_r ; t1 = silu(pre) ; m = silu(t1@ew2+b2)*s[src]
// msum[dst] = sum m ; gamma = m@cw+cb ; cu[dst] = sum gamma*dir.  No atomics.
// ---------------------------------------------------------------------------
__global__ __launch_bounds__(256) void edge_kernel(
    const float* __restrict__ A, const float* __restrict__ Bm,
    const float* __restrict__ p, const float* __restrict__ s,
    const int* __restrict__ csr_off, const int* __restrict__ eid,
    const float* __restrict__ wr, const float* __restrict__ ew2,
    const float* __restrict__ eb2, const float* __restrict__ cw,
    const float* __restrict__ cbp, float* __restrict__ msum,
    float* __restrict__ cu) {
  __shared__ float w2s[H][H];        // 64 KB
  __shared__ float t1T[H][KNN];      // [c][e], 8 KB
  __shared__ float wrs[H], cws[H], b2s[H];
  __shared__ float r2A[KNN], sA[KNN], dirA[KNN][3];
  __shared__ int srcA[KNN];
  __shared__ float gammaP[2][KNN];
  __shared__ float gA[KNN];
  __shared__ float msumC[H];
  int tid = threadIdx.x;
  for (int i = tid; i < H * H / 4; i += 256)
    ((float4*)w2s)[i] = ((const float4*)ew2)[i];
  if (tid < H) { wrs[tid] = wr[tid]; cws[tid] = cw[tid]; b2s[tid] = eb2[tid]; }
  float cb = cbp[0];
  int o = tid & 127;
  int ehalf = tid >> 7;
  int eh = ehalf * 8;
  int lane = tid & 63;
  int wid = tid >> 6;

  for (int nd = 0; nd < 4; ++nd) {
    int d = blockIdx.x * 4 + nd;
    int off0 = csr_off[d], off1 = csr_off[d + 1];
    int deg = off1 - off0;
    float msum_reg = 0.0f;
    float cuacc = 0.0f;  // used by tid<3

    for (int g0 = 0; g0 < deg; g0 += KNN) {
      int ne = min(KNN, deg - g0);
      __syncthreads();  // protect LDS reuse (geometry/gA/dirA consumed below)
      if (tid < KNN) {
        int e = tid;
        if (e < ne) {
          int edge = eid[off0 + g0 + e];
          int src = edge / KNN;
          srcA[e] = src;
          float dx = p[d * 3 + 0] - p[src * 3 + 0];
          float dy = p[d * 3 + 1] - p[src * 3 + 1];
          float dz = p[d * 3 + 2] - p[src * 3 + 2];
          float r2 = dx * dx + dy * dy + dz * dz;
          r2A[e] = r2;
          float rinv = 1.0f / sqrtf(r2 + 1e-8f);
          dirA[e][0] = dx * rinv;
          dirA[e][1] = dy * rinv;
          dirA[e][2] = dz * rinv;
          sA[e] = s[src];
        } else {
          srcA[e] = d;
          r2A[e] = 0.0f;
          sA[e] = 0.0f;  // padded edge: m -> 0, dir -> 0
          dirA[e][0] = dirA[e][1] = dirA[e][2] = 0.0f;
        }
      }
      __syncthreads();
      // phase 1: t1 (transposed into LDS)
      {
        int el = tid & 15, cg = tid >> 4;
        int src = srcA[el];
        float r2v = r2A[el];
#pragma unroll
        for (int k = 0; k < 8; ++k) {
          int c = cg * 8 + k;
          float pre = A[d * H + c] + Bm[src * H + c] + r2v * wrs[c];
          t1T[c][el] = silu(pre);
        }
      }
      __syncthreads();
      // phase 2: m[e][o] = silu(t1 @ ew2 + b2) * s[src]
      float m[8];
#pragma unroll
      for (int j = 0; j < 8; ++j) m[j] = b2s[o];
      for (int c = 0; c < H; ++c) {
        float w = w2s[c][o];
        float4 ta = *(const float4*)&t1T[c][eh];
        float4 tb = *(const float4*)&t1T[c][eh + 4];
        m[0] = fmaf(ta.x, w, m[0]);
        m[1] = fmaf(ta.y, w, m[1]);
        m[2] = fmaf(ta.z, w, m[2]);
        m[3] = fmaf(ta.w, w, m[3]);
        m[4] = fmaf(tb.x, w, m[4]);
        m[5] = fmaf(tb.y, w, m[5]);
        m[6] = fmaf(tb.z, w, m[6]);
        m[7] = fmaf(tb.w, w, m[7]);
      }
#pragma unroll
      for (int j = 0; j < 8; ++j) {
        m[j] = silu(m[j]) * sA[eh + j];
        msum_reg += m[j];
      }
      // gamma partials: reduce m[e][o]*cw[o] over each wave's 64 o-lanes
#pragma unroll
      for (int j = 0; j < 8; ++j) {
        float v = m[j] * cws[o];
#pragma unroll
        for (int sft = 32; sft > 0; sft >>= 1) v += __shfl_xor(v, sft, 64);
        if (lane == 0) gammaP[wid & 1][eh + j] = v;
      }
      __syncthreads();
      if (tid < KNN) gA[tid] = gammaP[0][tid] + gammaP[1][tid] + cb;
      __syncthreads();
      if (tid < 3) {
        float acc = 0.0f;
        for (int e = 0; e < ne; ++e) acc += gA[e] * dirA[e][tid];
        cuacc += acc;
      }
    }  // groups

    __syncthreads();
    if (ehalf == 0) msumC[o] = msum_reg;
    __syncthreads();
    if (ehalf == 1) msum[d * H + o] = msumC[o] + msum_reg;
    if (tid < 3) cu[d * 3 + tid] = cuacc;
  }  // nodes
}

// ---------------------------------------------------------------------------
// Node update: h_new = silu(cat(h, msum/deg) @ nw1 + nb1) @ nw2 + nb2
// p_new = p + cu/deg.  8 nodes per block.
// ---------------------------------------------------------------------------
__global__ __launch_bounds__(256) void node_kernel(
    const float* __restrict__ h, const float* __restrict__ msum,
    const int* __restrict__ degi, const float* __restrict__ cu,
    const float* __restrict__ p_in, const float* __restrict__ nw1,
    const float* __restrict__ nb1, const float* __restrict__ nw2,
    const float* __restrict__ nb2, float* __restrict__ h_out,
    float* __restrict__ p_out) {
  __shared__ float ins[8][2 * H];
  __shared__ float hns[8][H];
  int tid = threadIdx.x;
  int n0 = blockIdx.x * 8;
  for (int idx = tid; idx < 8 * 2 * H; idx += 256) {
    int n = idx >> 8, c = idx & 255;
    int gn = n0 + n;
    float v;
    if (c < H) v = h[gn * H + c];
    else {
      float dg = (float)max(degi[gn], 1);
      v = msum[gn * H + (c - H)] / dg;
    }
    ins[n][c] = v;
  }
  __syncthreads();
  int o = tid & 127, ng = (tid >> 7) * 4;
  float acc[4];
#pragma unroll
  for (int n = 0; n < 4; ++n) acc[n] = nb1[o];
  for (int c = 0; c < 2 * H; c += 4) {
    float4 wv;
    wv.x = nw1[(c + 0) * H + o];
    wv.y = nw1[(c + 1) * H + o];
    wv.z = nw1[(c + 2) * H + o];
    wv.w = nw1[(c + 3) * H + o];
#pragma unroll
    for (int n = 0; n < 4; ++n) {
      float4 hv = *(const float4*)&ins[ng + n][c];
      acc[n] = fmaf(hv.x, wv.x, acc[n]);
      acc[n] = fmaf(hv.y, wv.y, acc[n]);
      acc[n] = fmaf(hv.z, wv.z, acc[n]);
      acc[n] = fmaf(hv.w, wv.w, acc[n]);
    }
  }
#pragma unroll
  for (int n = 0; n < 4; ++n) hns[ng + n][o] = silu(acc[n]);
  __syncthreads();
  float acc2[4];
#pragma unroll
  for (int n = 0; n < 4; ++n) acc2[n] = nb2[o];
  for (int c = 0; c < H; c += 4) {
    float4 wv;
    wv.x = nw2[(c + 0) * H + o];
    wv.y = nw2[(c + 1) * H + o];
    wv.z = nw2[(c + 2) * H + o];
    wv.w = nw2[(c + 3) * H + o];
#pragma unroll
    for (int n = 0; n < 4; ++n) {
      float4 hv = *(const float4*)&hns[ng + n][c];
      acc2[n] = fmaf(hv.x, wv.x, acc2[n]);
      acc2[n] = fmaf(hv.y, wv.y, acc2[n]);
      acc2[n] = fmaf(hv.z, wv.z, acc2[n]);
      acc2[n] = fmaf(hv.w, wv.w, acc2[n]);
    }
  }
#pragma unroll
  for (int n = 0; n < 4; ++n) h_out[(n0 + ng + n) * H + o] = acc2[n];
  if (tid < 24) {
    int nl = tid / 3, comp = tid % 3;
    int gn = n0 + nl;
    float dg = (float)max(degi[gn], 1);
    p_out[gn * 3 + comp] = p_in[gn * 3 + comp] + cu[gn * 3 + comp] / dg;
  }
}

// ---------------------------------------------------------------------------
// Output head: [eps_c | eps_f | p] per node. 32 nodes per block.
// ---------------------------------------------------------------------------
__global__ __launch_bounds__(256) void out_kernel(
    const float* __restrict__ h, const float* __restrict__ p,
    const float* __restrict__ ecw, const float* __restrict__ ecb,
    const float* __restrict__ efw, const float* __restrict__ efb,
    float* __restrict__ out) {
  __shared__ float hs[32][H];
  int tid = threadIdx.x, n0 = blockIdx.x * 32;
  for (int idx = tid; idx < 32 * H; idx += 256) {
    int n = idx >> 7, c = idx & 127;
    int gn = n0 + n;
    hs[n][c] = (gn < N_NODES) ? h[gn * H + c] : 0.0f;
  }
  __syncthreads();
  for (int f = tid; f < 32 * 70; f += 256) {
    int nl = f / 70, j = f % 70;
    int gn = n0 + nl;
    if (gn >= N_NODES) continue;
    float v;
    if (j < 3) {
      v = ecb[j];
      for (int c = 0; c < H; ++c) v = fmaf(hs[nl][c], ecw[c * 3 + j], v);
    } else if (j < 67) {
      int jj = j - 3;
      v = efb[jj];
      for (int c = 0; c < H; ++c) v = fmaf(hs[nl][c], efw[c * ND + jj], v);
    } else {
      v = p[gn * 3 + (j - 67)];
    }
    out[gn * 70 + j] = v;
  }
}

// ---------------------------------------------------------------------------
extern "C" void kernel_launch(void* const* d_in, const int* in_sizes, int n_in,
                              void* d_out, int out_size, void* d_ws, size_t ws_size,
                              hipStream_t stream) {
  const float* x = (const float*)d_in[0];
  const float* pos = (const float*)d_in[1];
  const float* t = (const float*)d_in[2];
  const float* s = (const float*)d_in[3];
  const float* pw = (const float*)d_in[4];
  const float* pb = (const float*)d_in[5];
  const float* ew1 = (const float*)d_in[6];
  const float* eb1 = (const float*)d_in[7];
  const float* ew2 = (const float*)d_in[8];
  const float* eb2 = (const float*)d_in[9];
  const float* nw1 = (const float*)d_in[10];
  const float* nb1 = (const float*)d_in[11];
  const float* nw2 = (const float*)d_in[12];
  const float* nb2 = (const float*)d_in[13];
  const float* cw = (const float*)d_in[14];
  const float* cb = (const float*)d_in[15];
  const float* ecw = (const float*)d_in[16];
  const float* ecb = (const float*)d_in[17];
  const float* efw = (const float*)d_in[18];
  const float* efb = (const float*)d_in[19];

  char* wp = (char*)d_ws;
  auto alloc = [&](size_t bytes) {
    char* r = wp;
    wp += (bytes + 255) & ~(size_t)255;
    return r;
  };
  float* h0 = (float*)alloc((size_t)N_NODES * H * 4);
  float* h1 = (float*)alloc((size_t)N_NODES * H * 4);
  float* Abuf = (float*)alloc((size_t)N_NODES * H * 4);
  float* Bbuf = (float*)alloc((size_t)N_NODES * H * 4);
  float* msum = (float*)alloc((size_t)N_NODES * H * 4);
  float* p0 = (float*)alloc((size_t)N_NODES * 3 * 4);
  float* p1 = (float*)alloc((size_t)N_NODES * 3 * 4);
  float* cu = (float*)alloc((size_t)N_NODES * 3 * 4);
  int* degi = (int*)alloc((size_t)N_NODES * 4);
  int* nbr = (int*)alloc((size_t)E_EDGES * 4);
  int* off = (int*)alloc((size_t)(N_NODES + 1) * 4);
  int* cursor = (int*)alloc((size_t)N_NODES * 4);
  int* eid = (int*)alloc((size_t)E_EDGES * 4);

  hipMemsetAsync(degi, 0, (size_t)N_NODES * 4, stream);
  knn_kernel<<<(N_NODES + 255) / 256, 256, 0, stream>>>(pos, nbr);
  deg_count_kernel<<<(E_EDGES + 255) / 256, 256, 0, stream>>>(nbr, degi);
  scan_kernel<<<1, 1024, 0, stream>>>(degi, off, cursor);
  scatter_kernel<<<(E_EDGES + 255) / 256, 256, 0, stream>>>(nbr, cursor, eid);
  sort_kernel<<<(N_NODES + 255) / 256, 256, 0, stream>>>(off, eid);
  hipMemcpyAsync(p0, pos, (size_t)N_NODES * 3 * 4, hipMemcpyDeviceToDevice, stream);
  proj_kernel<<<N_NODES / 2, 256, 0, stream>>>(x, s, t, pw, pb, h0);

  float* hc = h0;
  float* hn = h1;
  float* pc = p0;
  float* pn = p1;
  for (int l = 0; l < LAYERS; ++l) {
    const float* ew1l = ew1 + (size_t)l * 257 * H;
    ab_kernel<<<N_NODES / 16, 256, 0, stream>>>(hc, ew1l, eb1 + l * H, Abuf, Bbuf);
    edge_kernel<<<N_NODES / 4, 256, 0, stream>>>(
        Abuf, Bbuf, pc, s, off, eid, ew1l + 256 * H, ew2 + (size_t)l * H * H,
        eb2 + l * H, cw + l * H, cb + l, msum, cu);
    node_kernel<<<N_NODES / 8, 256, 0, stream>>>(
        hc, msum, degi, cu, pc, nw1 + (size_t)l * 2 * H * H, nb1 + l * H,
        nw2 + (size_t)l * H * H, nb2 + l * H, hn, pn);
    float* tmp = hc; hc = hn; hn = tmp;
    tmp = pc; pc = pn; pn = tmp;
  }
  out_kernel<<<(N_NODES + 31) / 32, 256, 0, stream>>>(hc, pc, ecw, ecb, efw, efb,
                                                      (float*)d_out);
}

// Round 2
// 2197.775 us; speedup vs baseline: 1.9122x; 1.9122x over previous
//
#include <hip/hip_runtime.h>
#include <math.h>

#define N_NODES 10000
#define ND 64
#define H 128
#define LAYERS 4
#define KNN 16
#define TD 16
#define E_EDGES (N_NODES * KNN)
#define P_CHUNKS 16
#define CHUNK 625  // N_NODES / P_CHUNKS

__device__ __forceinline__ float silu(float x) { return x / (1.0f + __expf(-x)); }

// ---------------------------------------------------------------------------
// pos4 precompute: [x,y,z, x^2+y^2+z^2] per node
// ---------------------------------------------------------------------------
__global__ __launch_bounds__(256) void pos4_kernel(const float* __restrict__ pos,
                                                   float4* __restrict__ pos4) {
  int i = blockIdx.x * 256 + threadIdx.x;
  if (i >= N_NODES) return;
  float x = pos[i * 3 + 0], y = pos[i * 3 + 1], z = pos[i * 3 + 2];
  pos4[i] = make_float4(x, y, z, x * x + y * y + z * z);
}

// ---------------------------------------------------------------------------
// KNN partial: grid (P_CHUNKS, 40). Each block stages one 625-candidate chunk
// in LDS (10KB); each thread keeps top-16 of that chunk for its query node.
// d2 = sq_i + sq_j - 2*dot (reference formula); strict < keeps earliest index.
// ---------------------------------------------------------------------------
__global__ __launch_bounds__(256) void knn_part_kernel(
    const float4* __restrict__ pos4, float* __restrict__ pd,
    int* __restrict__ pi) {
  __shared__ float4 C[CHUNK];
  int c = blockIdx.x;
  int qb = blockIdx.y;
  int tid = threadIdx.x;
  int base = c * CHUNK;
  for (int j = tid; j < CHUNK; j += 256) C[j] = pos4[base + j];
  __syncthreads();
  int i = qb * 256 + tid;
  if (i >= N_NODES) return;
  float4 q = pos4[i];
  float bd[KNN];
  int bi[KNN];
#pragma unroll
  for (int k = 0; k < KNN; ++k) { bd[k] = __builtin_inff(); bi[k] = 0; }
#pragma unroll 4
  for (int j = 0; j < CHUNK; ++j) {
    float4 p = C[j];
    float d2 = q.w + p.w - 2.0f * (q.x * p.x + q.y * p.y + q.z * p.z);
    int gj = base + j;
    if (gj == i) d2 = __builtin_inff();
    if (d2 < bd[KNN - 1]) {
#pragma unroll
      for (int k = KNN - 1; k >= 1; --k) {
        bool stay = (bd[k] <= d2);
        bool here = (bd[k - 1] <= d2);
        float nd = stay ? bd[k] : (here ? d2 : bd[k - 1]);
        int ni = stay ? bi[k] : (here ? gj : bi[k - 1]);
        bd[k] = nd;
        bi[k] = ni;
      }
      if (bd[0] > d2) { bd[0] = d2; bi[0] = gj; }
    }
  }
  float* po = pd + ((size_t)i * P_CHUNKS + c) * KNN;
  int* io = pi + ((size_t)i * P_CHUNKS + c) * KNN;
#pragma unroll
  for (int k = 0; k < KNN; ++k) { po[k] = bd[k]; io[k] = bi[k]; }
}

// ---------------------------------------------------------------------------
// KNN merge: per query, merge 16 sorted partial lists (chunk-ascending order
// preserves lowest-index-wins on ties). Early break per chunk (lists sorted).
// ---------------------------------------------------------------------------
__global__ __launch_bounds__(256) void knn_merge_kernel(
    const float* __restrict__ pd, const int* __restrict__ pi,
    int* __restrict__ nbr) {
  int i = blockIdx.x * 256 + threadIdx.x;
  if (i >= N_NODES) return;
  const float* prow = pd + (size_t)i * P_CHUNKS * KNN;
  const int* irow = pi + (size_t)i * P_CHUNKS * KNN;
  float bd[KNN];
  int bi[KNN];
#pragma unroll
  for (int k = 0; k < KNN; ++k) { bd[k] = __builtin_inff(); bi[k] = 0; }
  for (int c = 0; c < P_CHUNKS; ++c) {
    for (int k2 = 0; k2 < KNN; ++k2) {
      float d2 = prow[c * KNN + k2];
      if (d2 >= bd[KNN - 1]) break;  // chunk list sorted ascending
      int gj = irow[c * KNN + k2];
#pragma unroll
      for (int k = KNN - 1; k >= 1; --k) {
        bool stay = (bd[k] <= d2);
        bool here = (bd[k - 1] <= d2);
        float nd = stay ? bd[k] : (here ? d2 : bd[k - 1]);
        int ni = stay ? bi[k] : (here ? gj : bi[k - 1]);
        bd[k] = nd;
        bi[k] = ni;
      }
      if (bd[0] > d2) { bd[0] = d2; bi[0] = gj; }
    }
  }
#pragma unroll
  for (int k = 0; k < KNN; ++k) nbr[i * KNN + k] = bi[k];
}

// ---------------------------------------------------------------------------
// CSR build (deterministic): count -> scan -> scatter -> per-node sort
// ---------------------------------------------------------------------------
__global__ void deg_count_kernel(const int* __restrict__ nbr, int* __restrict__ degi) {
  int e = blockIdx.x * 256 + threadIdx.x;
  if (e < E_EDGES) atomicAdd(&degi[nbr[e]], 1);
}

__global__ __launch_bounds__(1024) void scan_kernel(const int* __restrict__ degi,
                                                    int* __restrict__ off,
                                                    int* __restrict__ cursor) {
  __shared__ int part[1024];
  int t = threadIdx.x;
  int base = t * 10;
  int sum = 0;
  if (t < 1000)
    for (int i = 0; i < 10; ++i) sum += degi[base + i];
  part[t] = sum;
  __syncthreads();
  for (int stp = 1; stp < 1024; stp <<= 1) {
    int v = (t >= stp) ? part[t - stp] : 0;
    __syncthreads();
    part[t] += v;
    __syncthreads();
  }
  if (t < 1000) {
    int run = (t == 0) ? 0 : part[t - 1];
    for (int i = 0; i < 10; ++i) {
      off[base + i] = run;
      cursor[base + i] = run;
      run += degi[base + i];
    }
  }
  if (t == 0) off[N_NODES] = E_EDGES;
}

__global__ void scatter_kernel(const int* __restrict__ nbr, int* __restrict__ cursor,
                               int* __restrict__ eid) {
  int e = blockIdx.x * 256 + threadIdx.x;
  if (e < E_EDGES) {
    int d = nbr[e];
    int p = atomicAdd(&cursor[d], 1);
    eid[p] = e;
  }
}

__global__ void sort_kernel(const int* __restrict__ off, int* __restrict__ eid) {
  int n = blockIdx.x * 256 + threadIdx.x;
  if (n >= N_NODES) return;
  int a = off[n], b = off[n + 1];
  for (int i = a + 1; i < b; ++i) {
    int v = eid[i];
    int j = i - 1;
    while (j >= a && eid[j] > v) { eid[j + 1] = eid[j]; --j; }
    eid[j + 1] = v;
  }
}

// ---------------------------------------------------------------------------
// Input projection: h0 = concat(x, s, temb) @ proj_w + proj_b. 2 nodes/block.
// ---------------------------------------------------------------------------
__global__ __launch_bounds__(256) void proj_kernel(const float* __restrict__ x,
                                                   const float* __restrict__ s,
                                                   const float* __restrict__ tptr,
                                                   const float* __restrict__ pw,
                                                   const float* __restrict__ pb,
                                                   float* __restrict__ h) {
  __shared__ float inp[2][81];
  int tid = threadIdx.x;
  int g = tid >> 7;
  int o = tid & 127;
  int node = blockIdx.x * 2 + g;
  float t = tptr[0];
  if (o < 64) inp[g][o] = x[node * ND + o];
  else if (o == 64) inp[g][64] = s[node];
  else if (o < 81) {
    int j = o - 65;
    int jj = (j < 8) ? j : (j - 8);
    float f = __expf(-4.0f * (float)jj / 7.0f);
    float a = t * f;
    inp[g][o] = (j < 8) ? sinf(a) : cosf(a);
  }
  __syncthreads();
  float acc = pb[o];
#pragma unroll
  for (int c = 0; c < 81; ++c) acc = fmaf(inp[g][c], pw[c * H + o], acc);
  h[node * H + o] = acc;
}

// ---------------------------------------------------------------------------
// A = h @ ew1[0:128] + eb1 ; B = h @ ew1[128:256].  16 nodes per block.
// ---------------------------------------------------------------------------
__global__ __launch_bounds__(256) void ab_kernel(const float* __restrict__ h,
                                                 const float* __restrict__ ew1,
                                                 const float* __restrict__ eb1,
                                                 float* __restrict__ A,
                                                 float* __restrict__ B) {
  __shared__ float hs[16][H];
  int tid = threadIdx.x;
  int n0 = blockIdx.x * 16;
  for (int idx = tid; idx < 16 * H; idx += 256) {
    int n = idx >> 7, c = idx & 127;
    hs[n][c] = h[(n0 + n) * H + c];
  }
  __syncthreads();
  int part = tid >> 7, o = tid & 127;
  const float* W = ew1 + part * H * H;
  float acc[16];
#pragma unroll
  for (int n = 0; n < 16; ++n) acc[n] = 0.0f;
  for (int c = 0; c < H; c += 4) {
    float4 wv;
    wv.x = W[(c + 0) * H + o];
    wv.y = W[(c + 1) * H + o];
    wv.z = W[(c + 2) * H + o];
    wv.w = W[(c + 3) * H + o];
#pragma unroll
    for (int n = 0; n < 16; ++n) {
      float4 hv = *(const float4*)&hs[n][c];
      acc[n] = fmaf(hv.x, wv.x, acc[n]);
      acc[n] = fmaf(hv.y, wv.y, acc[n]);
      acc[n] = fmaf(hv.z, wv.z, acc[n]);
      acc[n] = fmaf(hv.w, wv.w, acc[n]);
    }
  }
  float bias = (part == 0) ? eb1[o] : 0.0f;
  float* out = (part == 0) ? A : B;
#pragma unroll
  for (int n = 0; n < 16; ++n) out[(n0 + n) * H + o] = acc[n] + bias;
}

// ---------------------------------------------------------------------------
// Fused edge message + aggregation. 4 dst nodes per block; 16-edge groups.
// ---------------------------------------------------------------------------
__global__ __launch_bounds__(256) void edge_kernel(
    const float* __restrict__ A, const float* __restrict__ Bm,
    const float* __restrict__ p, const float* __restrict__ s,
    const int* __restrict__ csr_off, const int* __restrict__ eid,
    const float* __restrict__ wr, const float* __restrict__ ew2,
    const float* __restrict__ eb2, const float* __restrict__ cw,
    const float* __restrict__ cbp, float* __restrict__ msum,
    float* __restrict__ cu) {
  __shared__ float w2s[H][H];        // 64 KB
  __shared__ float t1T[H][KNN];      // [c][e], 8 KB
  __shared__ float wrs[H], cws[H], b2s[H];
  __shared__ float r2A[KNN], sA[KNN], dirA[KNN][3];
  __shared__ int srcA[KNN];
  __shared__ float gammaP[2][KNN];
  __shared__ float gA[KNN];
  __shared__ float msumC[H];
  int tid = threadIdx.x;
  for (int i = tid; i < H * H / 4; i += 256)
    ((float4*)w2s)[i] = ((const float4*)ew2)[i];
  if (tid < H) { wrs[tid] = wr[tid]; cws[tid] = cw[tid]; b2s[tid] = eb2[tid]; }
  float cb = cbp[0];
  int o = tid & 127;
  int ehalf = tid >> 7;
  int eh = ehalf * 8;
  int lane = tid & 63;
  int wid = tid >> 6;

  for (int nd = 0; nd < 4; ++nd) {
    int d = blockIdx.x * 4 + nd;
    int off0 = csr_off[d], off1 = csr_off[d + 1];
    int deg = off1 - off0;
    float msum_reg = 0.0f;
    float cuacc = 0.0f;  // used by tid<3

    for (int g0 = 0; g0 < deg; g0 += KNN) {
      int ne = min(KNN, deg - g0);
      __syncthreads();
      if (tid < KNN) {
        int e = tid;
        if (e < ne) {
          int edge = eid[off0 + g0 + e];
          int src = edge / KNN;
          srcA[e] = src;
          float dx = p[d * 3 + 0] - p[src * 3 + 0];
          float dy = p[d * 3 + 1] - p[src * 3 + 1];
          float dz = p[d * 3 + 2] - p[src * 3 + 2];
          float r2 = dx * dx + dy * dy + dz * dz;
          r2A[e] = r2;
          float rinv = 1.0f / sqrtf(r2 + 1e-8f);
          dirA[e][0] = dx * rinv;
          dirA[e][1] = dy * rinv;
          dirA[e][2] = dz * rinv;
          sA[e] = s[src];
        } else {
          srcA[e] = d;
          r2A[e] = 0.0f;
          sA[e] = 0.0f;
          dirA[e][0] = dirA[e][1] = dirA[e][2] = 0.0f;
        }
      }
      __syncthreads();
      {
        int el = tid & 15, cg = tid >> 4;
        int src = srcA[el];
        float r2v = r2A[el];
#pragma unroll
        for (int k = 0; k < 8; ++k) {
          int c = cg * 8 + k;
          float pre = A[d * H + c] + Bm[src * H + c] + r2v * wrs[c];
          t1T[c][el] = silu(pre);
        }
      }
      __syncthreads();
      float m[8];
#pragma unroll
      for (int j = 0; j < 8; ++j) m[j] = b2s[o];
      for (int c = 0; c < H; ++c) {
        float w = w2s[c][o];
        float4 ta = *(const float4*)&t1T[c][eh];
        float4 tb = *(const float4*)&t1T[c][eh + 4];
        m[0] = fmaf(ta.x, w, m[0]);
        m[1] = fmaf(ta.y, w, m[1]);
        m[2] = fmaf(ta.z, w, m[2]);
        m[3] = fmaf(ta.w, w, m[3]);
        m[4] = fmaf(tb.x, w, m[4]);
        m[5] = fmaf(tb.y, w, m[5]);
        m[6] = fmaf(tb.z, w, m[6]);
        m[7] = fmaf(tb.w, w, m[7]);
      }
#pragma unroll
      for (int j = 0; j < 8; ++j) {
        m[j] = silu(m[j]) * sA[eh + j];
        msum_reg += m[j];
      }
#pragma unroll
      for (int j = 0; j < 8; ++j) {
        float v = m[j] * cws[o];
#pragma unroll
        for (int sft = 32; sft > 0; sft >>= 1) v += __shfl_xor(v, sft, 64);
        if (lane == 0) gammaP[wid & 1][eh + j] = v;
      }
      __syncthreads();
      if (tid < KNN) gA[tid] = gammaP[0][tid] + gammaP[1][tid] + cb;
      __syncthreads();
      if (tid < 3) {
        float acc = 0.0f;
        for (int e = 0; e < ne; ++e) acc += gA[e] * dirA[e][tid];
        cuacc += acc;
      }
    }  // groups

    __syncthreads();
    if (ehalf == 0) msumC[o] = msum_reg;
    __syncthreads();
    if (ehalf == 1) msum[d * H + o] = msumC[o] + msum_reg;
    if (tid < 3) cu[d * 3 + tid] = cuacc;
  }  // nodes
}

// ---------------------------------------------------------------------------
// Node update
// ---------------------------------------------------------------------------
__global__ __launch_bounds__(256) void node_kernel(
    const float* __restrict__ h, const float* __restrict__ msum,
    const int* __restrict__ degi, const float* __restrict__ cu,
    const float* __restrict__ p_in, const float* __restrict__ nw1,
    const float* __restrict__ nb1, const float* __restrict__ nw2,
    const float* __restrict__ nb2, float* __restrict__ h_out,
    float* __restrict__ p_out) {
  __shared__ float ins[8][2 * H];
  __shared__ float hns[8][H];
  int tid = threadIdx.x;
  int n0 = blockIdx.x * 8;
  for (int idx = tid; idx < 8 * 2 * H; idx += 256) {
    int n = idx >> 8, c = idx & 255;
    int gn = n0 + n;
    float v;
    if (c < H) v = h[gn * H + c];
    else {
      float dg = (float)max(degi[gn], 1);
      v = msum[gn * H + (c - H)] / dg;
    }
    ins[n][c] = v;
  }
  __syncthreads();
  int o = tid & 127, ng = (tid >> 7) * 4;
  float acc[4];
#pragma unroll
  for (int n = 0; n < 4; ++n) acc[n] = nb1[o];
  for (int c = 0; c < 2 * H; c += 4) {
    float4 wv;
    wv.x = nw1[(c + 0) * H + o];
    wv.y = nw1[(c + 1) * H + o];
    wv.z = nw1[(c + 2) * H + o];
    wv.w = nw1[(c + 3) * H + o];
#pragma unroll
    for (int n = 0; n < 4; ++n) {
      float4 hv = *(const float4*)&ins[ng + n][c];
      acc[n] = fmaf(hv.x, wv.x, acc[n]);
      acc[n] = fmaf(hv.y, wv.y, acc[n]);
      acc[n] = fmaf(hv.z, wv.z, acc[n]);
      acc[n] = fmaf(hv.w, wv.w, acc[n]);
    }
  }
#pragma unroll
  for (int n = 0; n < 4; ++n) hns[ng + n][o] = silu(acc[n]);
  __syncthreads();
  float acc2[4];
#pragma unroll
  for (int n = 0; n < 4; ++n) acc2[n] = nb2[o];
  for (int c = 0; c < H; c += 4) {
    float4 wv;
    wv.x = nw2[(c + 0) * H + o];
    wv.y = nw2[(c + 1) * H + o];
    wv.z = nw2[(c + 2) * H + o];
    wv.w = nw2[(c + 3) * H + o];
#pragma unroll
    for (int n = 0; n < 4; ++n) {
      float4 hv = *(const float4*)&hns[ng + n][c];
      acc2[n] = fmaf(hv.x, wv.x, acc2[n]);
      acc2[n] = fmaf(hv.y, wv.y, acc2[n]);
      acc2[n] = fmaf(hv.z, wv.z, acc2[n]);
      acc2[n] = fmaf(hv.w, wv.w, acc2[n]);
    }
  }
#pragma unroll
  for (int n = 0; n < 4; ++n) h_out[(n0 + ng + n) * H + o] = acc2[n];
  if (tid < 24) {
    int nl = tid / 3, comp = tid % 3;
    int gn = n0 + nl;
    float dg = (float)max(degi[gn], 1);
    p_out[gn * 3 + comp] = p_in[gn * 3 + comp] + cu[gn * 3 + comp] / dg;
  }
}

// ---------------------------------------------------------------------------
// Output head
// ---------------------------------------------------------------------------
__global__ __launch_bounds__(256) void out_kernel(
    const float* __restrict__ h, const float* __restrict__ p,
    const float* __restrict__ ecw, const float* __restrict__ ecb,
    const float* __restrict__ efw, const float* __restrict__ efb,
    float* __restrict__ out) {
  __shared__ float hs[32][H];
  int tid = threadIdx.x, n0 = blockIdx.x * 32;
  for (int idx = tid; idx < 32 * H; idx += 256) {
    int n = idx >> 7, c = idx & 127;
    int gn = n0 + n;
    hs[n][c] = (gn < N_NODES) ? h[gn * H + c] : 0.0f;
  }
  __syncthreads();
  for (int f = tid; f < 32 * 70; f += 256) {
    int nl = f / 70, j = f % 70;
    int gn = n0 + nl;
    if (gn >= N_NODES) continue;
    float v;
    if (j < 3) {
      v = ecb[j];
      for (int c = 0; c < H; ++c) v = fmaf(hs[nl][c], ecw[c * 3 + j], v);
    } else if (j < 67) {
      int jj = j - 3;
      v = efb[jj];
      for (int c = 0; c < H; ++c) v = fmaf(hs[nl][c], efw[c * ND + jj], v);
    } else {
      v = p[gn * 3 + (j - 67)];
    }
    out[gn * 70 + j] = v;
  }
}

// ---------------------------------------------------------------------------
extern "C" void kernel_launch(void* const* d_in, const int* in_sizes, int n_in,
                              void* d_out, int out_size, void* d_ws, size_t ws_size,
                              hipStream_t stream) {
  const float* x = (const float*)d_in[0];
  const float* pos = (const float*)d_in[1];
  const float* t = (const float*)d_in[2];
  const float* s = (const float*)d_in[3];
  const float* pw = (const float*)d_in[4];
  const float* pb = (const float*)d_in[5];
  const float* ew1 = (const float*)d_in[6];
  const float* eb1 = (const float*)d_in[7];
  const float* ew2 = (const float*)d_in[8];
  const float* eb2 = (const float*)d_in[9];
  const float* nw1 = (const float*)d_in[10];
  const float* nb1 = (const float*)d_in[11];
  const float* nw2 = (const float*)d_in[12];
  const float* nb2 = (const float*)d_in[13];
  const float* cw = (const float*)d_in[14];
  const float* cb = (const float*)d_in[15];
  const float* ecw = (const float*)d_in[16];
  const float* ecb = (const float*)d_in[17];
  const float* efw = (const float*)d_in[18];
  const float* efb = (const float*)d_in[19];

  char* wp = (char*)d_ws;
  auto alloc = [&](size_t bytes) {
    char* r = wp;
    wp += (bytes + 255) & ~(size_t)255;
    return r;
  };
  float* h0 = (float*)alloc((size_t)N_NODES * H * 4);
  float* h1 = (float*)alloc((size_t)N_NODES * H * 4);
  float* Abuf = (float*)alloc((size_t)N_NODES * H * 4);
  float* Bbuf = (float*)alloc((size_t)N_NODES * H * 4);
  float* msum = (float*)alloc((size_t)N_NODES * H * 4);
  float* p0 = (float*)alloc((size_t)N_NODES * 3 * 4);
  float* p1 = (float*)alloc((size_t)N_NODES * 3 * 4);
  float* cu = (float*)alloc((size_t)N_NODES * 3 * 4);
  int* degi = (int*)alloc((size_t)N_NODES * 4);
  int* nbr = (int*)alloc((size_t)E_EDGES * 4);
  int* off = (int*)alloc((size_t)(N_NODES + 1) * 4);
  int* cursor = (int*)alloc((size_t)N_NODES * 4);
  int* eid = (int*)alloc((size_t)E_EDGES * 4);

  // KNN scratch aliases layer buffers (all written only after graph build):
  // pd spans h0+h1 (10.24MB needed, 10.24MB available, contiguous);
  // pi spans Abuf+Bbuf; pos4 sits at msum.
  float* pd = h0;
  int* pi = (int*)Abuf;
  float4* pos4 = (float4*)msum;

  hipMemsetAsync(degi, 0, (size_t)N_NODES * 4, stream);
  pos4_kernel<<<(N_NODES + 255) / 256, 256, 0, stream>>>(pos, pos4);
  {
    dim3 g(P_CHUNKS, (N_NODES + 255) / 256);
    knn_part_kernel<<<g, 256, 0, stream>>>(pos4, pd, pi);
  }
  knn_merge_kernel<<<(N_NODES + 255) / 256, 256, 0, stream>>>(pd, pi, nbr);
  deg_count_kernel<<<(E_EDGES + 255) / 256, 256, 0, stream>>>(nbr, degi);
  scan_kernel<<<1, 1024, 0, stream>>>(degi, off, cursor);
  scatter_kernel<<<(E_EDGES + 255) / 256, 256, 0, stream>>>(nbr, cursor, eid);
  sort_kernel<<<(N_NODES + 255) / 256, 256, 0, stream>>>(off, eid);
  hipMemcpyAsync(p0, pos, (size_t)N_NODES * 3 * 4, hipMemcpyDeviceToDevice, stream);
  proj_kernel<<<N_NODES / 2, 256, 0, stream>>>(x, s, t, pw, pb, h0);

  float* hc = h0;
  float* hn = h1;
  float* pc = p0;
  float* pn = p1;
  for (int l = 0; l < LAYERS; ++l) {
    const float* ew1l = ew1 + (size_t)l * 257 * H;
    ab_kernel<<<N_NODES / 16, 256, 0, stream>>>(hc, ew1l, eb1 + l * H, Abuf, Bbuf);
    edge_kernel<<<N_NODES / 4, 256, 0, stream>>>(
        Abuf, Bbuf, pc, s, off, eid, ew1l + 256 * H, ew2 + (size_t)l * H * H,
        eb2 + l * H, cw + l * H, cb + l, msum, cu);
    node_kernel<<<N_NODES / 8, 256, 0, stream>>>(
        hc, msum, degi, cu, pc, nw1 + (size_t)l * 2 * H * H, nb1 + l * H,
        nw2 + (size_t)l * H * H, nb2 + l * H, hn, pn);
    float* tmp = hc; hc = hn; hn = tmp;
    tmp = pc; pc = pn; pn = tmp;
  }
  out_kernel<<<(N_NODES + 31) / 32, 256, 0, stream>>>(hc, pc, ecw, ecb, efw, efb,
                                                      (float*)d_out);
}

// Round 3
// 1745.154 us; speedup vs baseline: 2.4081x; 1.2594x over previous
//
#include <hip/hip_runtime.h>
#include <math.h>

#define N_NODES 10000
#define ND 64
#define H 128
#define LAYERS 4
#define KNN 16
#define TD 16
#define E_EDGES (N_NODES * KNN)
#define KC 2500  // candidates staged per LDS chunk (40 KB)

__device__ __forceinline__ float silu(float x) { return x / (1.0f + __expf(-x)); }

// ---------------------------------------------------------------------------
// pos4 precompute: [x,y,z, x^2+y^2+z^2] per node
// ---------------------------------------------------------------------------
__global__ __launch_bounds__(256) void pos4_kernel(const float* __restrict__ pos,
                                                   float4* __restrict__ pos4) {
  int i = blockIdx.x * 256 + threadIdx.x;
  if (i >= N_NODES) return;
  float x = pos[i * 3 + 0], y = pos[i * 3 + 1], z = pos[i * 3 + 2];
  pos4[i] = make_float4(x, y, z, x * x + y * y + z * z);
}

// ---------------------------------------------------------------------------
// KNN, wave-cooperative: one query per wave (4 waves/block). Top-16 held
// DISTRIBUTED across lanes 0..15 (sorted ascending). Each iteration 64 lanes
// evaluate 64 candidates; ballot isolates passers (rare after warmup); each
// passer is broadcast and inserted via a constant-cost distributed shift.
// d2 = sq_i + sq_j - 2*dot (reference formula). Strict < on the threshold +
// "stay if v <= d2b" preserves lowest-index-wins ties (ascending scan order).
// ---------------------------------------------------------------------------
__global__ __launch_bounds__(256) void knn_kernel(const float4* __restrict__ pos4,
                                                  int* __restrict__ nbr) {
  __shared__ float4 C[KC];  // 40000 B
  int tid = threadIdx.x;
  int lane = tid & 63;
  int wid = tid >> 6;
  int i = blockIdx.x * 4 + wid;  // 2500 blocks * 4 = 10000 exact
  float4 q = pos4[i];
  float v = __builtin_inff();  // lanes 0..15: sorted top-16 distances
  int vid = 0;
  float thresh = __builtin_inff();
  for (int base = 0; base < N_NODES; base += KC) {
    int cnt = min(KC, N_NODES - base);
    __syncthreads();
    for (int jj = tid; jj < cnt; jj += 256) C[jj] = pos4[base + jj];
    __syncthreads();
    for (int j0 = 0; j0 < cnt; j0 += 64) {
      int jl = j0 + lane;
      float d2 = __builtin_inff();
      if (jl < cnt) {
        float4 p = C[jl];
        d2 = q.w + p.w - 2.0f * (q.x * p.x + q.y * p.y + q.z * p.z);
        if (base + jl == i) d2 = __builtin_inff();
      }
      unsigned long long mask = __ballot(d2 < thresh);
      while (mask) {
        int sl = __ffsll((long long)mask) - 1;
        mask &= mask - 1;
        float d2b = __shfl(d2, sl, 64);
        if (d2b >= thresh) continue;  // wave-uniform (thresh tightened)
        int gjb = base + j0 + sl;
        float prevv = __shfl_up(v, 1, 64);
        int previd = __shfl_up(vid, 1, 64);
        bool stay = (v <= d2b);
        bool takenew = (lane == 0) || (prevv <= d2b);
        v = stay ? v : (takenew ? d2b : prevv);
        vid = stay ? vid : (takenew ? gjb : previd);
        thresh = __shfl(v, 15, 64);
      }
    }
  }
  if (lane < KNN) nbr[i * KNN + lane] = vid;
}

// ---------------------------------------------------------------------------
// CSR build (deterministic): count -> scan -> scatter -> per-node sort
// ---------------------------------------------------------------------------
__global__ void deg_count_kernel(const int* __restrict__ nbr, int* __restrict__ degi) {
  int e = blockIdx.x * 256 + threadIdx.x;
  if (e < E_EDGES) atomicAdd(&degi[nbr[e]], 1);
}

__global__ __launch_bounds__(1024) void scan_kernel(const int* __restrict__ degi,
                                                    int* __restrict__ off,
                                                    int* __restrict__ cursor) {
  __shared__ int part[1024];
  int t = threadIdx.x;
  int base = t * 10;
  int sum = 0;
  if (t < 1000)
    for (int i = 0; i < 10; ++i) sum += degi[base + i];
  part[t] = sum;
  __syncthreads();
  for (int stp = 1; stp < 1024; stp <<= 1) {
    int v = (t >= stp) ? part[t - stp] : 0;
    __syncthreads();
    part[t] += v;
    __syncthreads();
  }
  if (t < 1000) {
    int run = (t == 0) ? 0 : part[t - 1];
    for (int i = 0; i < 10; ++i) {
      off[base + i] = run;
      cursor[base + i] = run;
      run += degi[base + i];
    }
  }
  if (t == 0) off[N_NODES] = E_EDGES;
}

__global__ void scatter_kernel(const int* __restrict__ nbr, int* __restrict__ cursor,
                               int* __restrict__ eid) {
  int e = blockIdx.x * 256 + threadIdx.x;
  if (e < E_EDGES) {
    int d = nbr[e];
    int p = atomicAdd(&cursor[d], 1);
    eid[p] = e;
  }
}

__global__ void sort_kernel(const int* __restrict__ off, int* __restrict__ eid) {
  int n = blockIdx.x * 256 + threadIdx.x;
  if (n >= N_NODES) return;
  int a = off[n], b = off[n + 1];
  for (int i = a + 1; i < b; ++i) {
    int v = eid[i];
    int j = i - 1;
    while (j >= a && eid[j] > v) { eid[j + 1] = eid[j]; --j; }
    eid[j + 1] = v;
  }
}

// ---------------------------------------------------------------------------
// Input projection: h0 = concat(x, s, temb) @ proj_w + proj_b. 2 nodes/block.
// ---------------------------------------------------------------------------
__global__ __launch_bounds__(256) void proj_kernel(const float* __restrict__ x,
                                                   const float* __restrict__ s,
                                                   const float* __restrict__ tptr,
                                                   const float* __restrict__ pw,
                                                   const float* __restrict__ pb,
                                                   float* __restrict__ h) {
  __shared__ float inp[2][81];
  int tid = threadIdx.x;
  int g = tid >> 7;
  int o = tid & 127;
  int node = blockIdx.x * 2 + g;
  float t = tptr[0];
  if (o < 64) inp[g][o] = x[node * ND + o];
  else if (o == 64) inp[g][64] = s[node];
  else if (o < 81) {
    int j = o - 65;
    int jj = (j < 8) ? j : (j - 8);
    float f = __expf(-4.0f * (float)jj / 7.0f);
    float a = t * f;
    inp[g][o] = (j < 8) ? sinf(a) : cosf(a);
  }
  __syncthreads();
  float acc = pb[o];
#pragma unroll
  for (int c = 0; c < 81; ++c) acc = fmaf(inp[g][c], pw[c * H + o], acc);
  h[node * H + o] = acc;
}

// ---------------------------------------------------------------------------
// A = h @ ew1[0:128] + eb1 ; B = h @ ew1[128:256].  16 nodes per block.
// ---------------------------------------------------------------------------
__global__ __launch_bounds__(256) void ab_kernel(const float* __restrict__ h,
                                                 const float* __restrict__ ew1,
                                                 const float* __restrict__ eb1,
                                                 float* __restrict__ A,
                                                 float* __restrict__ B) {
  __shared__ float hs[16][H];
  int tid = threadIdx.x;
  int n0 = blockIdx.x * 16;
  for (int idx = tid; idx < 16 * H; idx += 256) {
    int n = idx >> 7, c = idx & 127;
    hs[n][c] = h[(n0 + n) * H + c];
  }
  __syncthreads();
  int part = tid >> 7, o = tid & 127;
  const float* W = ew1 + part * H * H;
  float acc[16];
#pragma unroll
  for (int n = 0; n < 16; ++n) acc[n] = 0.0f;
  for (int c = 0; c < H; c += 4) {
    float4 wv;
    wv.x = W[(c + 0) * H + o];
    wv.y = W[(c + 1) * H + o];
    wv.z = W[(c + 2) * H + o];
    wv.w = W[(c + 3) * H + o];
#pragma unroll
    for (int n = 0; n < 16; ++n) {
      float4 hv = *(const float4*)&hs[n][c];
      acc[n] = fmaf(hv.x, wv.x, acc[n]);
      acc[n] = fmaf(hv.y, wv.y, acc[n]);
      acc[n] = fmaf(hv.z, wv.z, acc[n]);
      acc[n] = fmaf(hv.w, wv.w, acc[n]);
    }
  }
  float bias = (part == 0) ? eb1[o] : 0.0f;
  float* out = (part == 0) ? A : B;
#pragma unroll
  for (int n = 0; n < 16; ++n) out[(n0 + n) * H + o] = acc[n] + bias;
}

// ---------------------------------------------------------------------------
// Fused edge message + aggregation. 4 dst nodes per block; 16-edge groups.
// ---------------------------------------------------------------------------
__global__ __launch_bounds__(256) void edge_kernel(
    const float* __restrict__ A, const float* __restrict__ Bm,
    const float* __restrict__ p, const float* __restrict__ s,
    const int* __restrict__ csr_off, const int* __restrict__ eid,
    const float* __restrict__ wr, const float* __restrict__ ew2,
    const float* __restrict__ eb2, const float* __restrict__ cw,
    const float* __restrict__ cbp, float* __restrict__ msum,
    float* __restrict__ cu) {
  __shared__ float w2s[H][H];        // 64 KB
  __shared__ float t1T[H][KNN];      // [c][e], 8 KB
  __shared__ float wrs[H], cws[H], b2s[H];
  __shared__ float r2A[KNN], sA[KNN], dirA[KNN][3];
  __shared__ int srcA[KNN];
  __shared__ float gammaP[2][KNN];
  __shared__ float gA[KNN];
  __shared__ float msumC[H];
  int tid = threadIdx.x;
  for (int i = tid; i < H * H / 4; i += 256)
    ((float4*)w2s)[i] = ((const float4*)ew2)[i];
  if (tid < H) { wrs[tid] = wr[tid]; cws[tid] = cw[tid]; b2s[tid] = eb2[tid]; }
  float cb = cbp[0];
  int o = tid & 127;
  int ehalf = tid >> 7;
  int eh = ehalf * 8;
  int lane = tid & 63;
  int wid = tid >> 6;

  for (int nd = 0; nd < 4; ++nd) {
    int d = blockIdx.x * 4 + nd;
    int off0 = csr_off[d], off1 = csr_off[d + 1];
    int deg = off1 - off0;
    float msum_reg = 0.0f;
    float cuacc = 0.0f;  // used by tid<3

    for (int g0 = 0; g0 < deg; g0 += KNN) {
      int ne = min(KNN, deg - g0);
      __syncthreads();
      if (tid < KNN) {
        int e = tid;
        if (e < ne) {
          int edge = eid[off0 + g0 + e];
          int src = edge / KNN;
          srcA[e] = src;
          float dx = p[d * 3 + 0] - p[src * 3 + 0];
          float dy = p[d * 3 + 1] - p[src * 3 + 1];
          float dz = p[d * 3 + 2] - p[src * 3 + 2];
          float r2 = dx * dx + dy * dy + dz * dz;
          r2A[e] = r2;
          float rinv = 1.0f / sqrtf(r2 + 1e-8f);
          dirA[e][0] = dx * rinv;
          dirA[e][1] = dy * rinv;
          dirA[e][2] = dz * rinv;
          sA[e] = s[src];
        } else {
          srcA[e] = d;
          r2A[e] = 0.0f;
          sA[e] = 0.0f;
          dirA[e][0] = dirA[e][1] = dirA[e][2] = 0.0f;
        }
      }
      __syncthreads();
      {
        int el = tid & 15, cg = tid >> 4;
        int src = srcA[el];
        float r2v = r2A[el];
#pragma unroll
        for (int k = 0; k < 8; ++k) {
          int c = cg * 8 + k;
          float pre = A[d * H + c] + Bm[src * H + c] + r2v * wrs[c];
          t1T[c][el] = silu(pre);
        }
      }
      __syncthreads();
      float m[8];
#pragma unroll
      for (int j = 0; j < 8; ++j) m[j] = b2s[o];
      for (int c = 0; c < H; ++c) {
        float w = w2s[c][o];
        float4 ta = *(const float4*)&t1T[c][eh];
        float4 tb = *(const float4*)&t1T[c][eh + 4];
        m[0] = fmaf(ta.x, w, m[0]);
        m[1] = fmaf(ta.y, w, m[1]);
        m[2] = fmaf(ta.z, w, m[2]);
        m[3] = fmaf(ta.w, w, m[3]);
        m[4] = fmaf(tb.x, w, m[4]);
        m[5] = fmaf(tb.y, w, m[5]);
        m[6] = fmaf(tb.z, w, m[6]);
        m[7] = fmaf(tb.w, w, m[7]);
      }
#pragma unroll
      for (int j = 0; j < 8; ++j) {
        m[j] = silu(m[j]) * sA[eh + j];
        msum_reg += m[j];
      }
#pragma unroll
      for (int j = 0; j < 8; ++j) {
        float v = m[j] * cws[o];
#pragma unroll
        for (int sft = 32; sft > 0; sft >>= 1) v += __shfl_xor(v, sft, 64);
        if (lane == 0) gammaP[wid & 1][eh + j] = v;
      }
      __syncthreads();
      if (tid < KNN) gA[tid] = gammaP[0][tid] + gammaP[1][tid] + cb;
      __syncthreads();
      if (tid < 3) {
        float acc = 0.0f;
        for (int e = 0; e < ne; ++e) acc += gA[e] * dirA[e][tid];
        cuacc += acc;
      }
    }  // groups

    __syncthreads();
    if (ehalf == 0) msumC[o] = msum_reg;
    __syncthreads();
    if (ehalf == 1) msum[d * H + o] = msumC[o] + msum_reg;
    if (tid < 3) cu[d * 3 + tid] = cuacc;
  }  // nodes
}

// ---------------------------------------------------------------------------
// Node update
// ---------------------------------------------------------------------------
__global__ __launch_bounds__(256) void node_kernel(
    const float* __restrict__ h, const float* __restrict__ msum,
    const int* __restrict__ degi, const float* __restrict__ cu,
    const float* __restrict__ p_in, const float* __restrict__ nw1,
    const float* __restrict__ nb1, const float* __restrict__ nw2,
    const float* __restrict__ nb2, float* __restrict__ h_out,
    float* __restrict__ p_out) {
  __shared__ float ins[8][2 * H];
  __shared__ float hns[8][H];
  int tid = threadIdx.x;
  int n0 = blockIdx.x * 8;
  for (int idx = tid; idx < 8 * 2 * H; idx += 256) {
    int n = idx >> 8, c = idx & 255;
    int gn = n0 + n;
    float v;
    if (c < H) v = h[gn * H + c];
    else {
      float dg = (float)max(degi[gn], 1);
      v = msum[gn * H + (c - H)] / dg;
    }
    ins[n][c] = v;
  }
  __syncthreads();
  int o = tid & 127, ng = (tid >> 7) * 4;
  float acc[4];
#pragma unroll
  for (int n = 0; n < 4; ++n) acc[n] = nb1[o];
  for (int c = 0; c < 2 * H; c += 4) {
    float4 wv;
    wv.x = nw1[(c + 0) * H + o];
    wv.y = nw1[(c + 1) * H + o];
    wv.z = nw1[(c + 2) * H + o];
    wv.w = nw1[(c + 3) * H + o];
#pragma unroll
    for (int n = 0; n < 4; ++n) {
      float4 hv = *(const float4*)&ins[ng + n][c];
      acc[n] = fmaf(hv.x, wv.x, acc[n]);
      acc[n] = fmaf(hv.y, wv.y, acc[n]);
      acc[n] = fmaf(hv.z, wv.z, acc[n]);
      acc[n] = fmaf(hv.w, wv.w, acc[n]);
    }
  }
#pragma unroll
  for (int n = 0; n < 4; ++n) hns[ng + n][o] = silu(acc[n]);
  __syncthreads();
  float acc2[4];
#pragma unroll
  for (int n = 0; n < 4; ++n) acc2[n] = nb2[o];
  for (int c = 0; c < H; c += 4) {
    float4 wv;
    wv.x = nw2[(c + 0) * H + o];
    wv.y = nw2[(c + 1) * H + o];
    wv.z = nw2[(c + 2) * H + o];
    wv.w = nw2[(c + 3) * H + o];
#pragma unroll
    for (int n = 0; n < 4; ++n) {
      float4 hv = *(const float4*)&hns[ng + n][c];
      acc2[n] = fmaf(hv.x, wv.x, acc2[n]);
      acc2[n] = fmaf(hv.y, wv.y, acc2[n]);
      acc2[n] = fmaf(hv.z, wv.z, acc2[n]);
      acc2[n] = fmaf(hv.w, wv.w, acc2[n]);
    }
  }
#pragma unroll
  for (int n = 0; n < 4; ++n) h_out[(n0 + ng + n) * H + o] = acc2[n];
  if (tid < 24) {
    int nl = tid / 3, comp = tid % 3;
    int gn = n0 + nl;
    float dg = (float)max(degi[gn], 1);
    p_out[gn * 3 + comp] = p_in[gn * 3 + comp] + cu[gn * 3 + comp] / dg;
  }
}

// ---------------------------------------------------------------------------
// Output head
// ---------------------------------------------------------------------------
__global__ __launch_bounds__(256) void out_kernel(
    const float* __restrict__ h, const float* __restrict__ p,
    const float* __restrict__ ecw, const float* __restrict__ ecb,
    const float* __restrict__ efw, const float* __restrict__ efb,
    float* __restrict__ out) {
  __shared__ float hs[32][H];
  int tid = threadIdx.x, n0 = blockIdx.x * 32;
  for (int idx = tid; idx < 32 * H; idx += 256) {
    int n = idx >> 7, c = idx & 127;
    int gn = n0 + n;
    hs[n][c] = (gn < N_NODES) ? h[gn * H + c] : 0.0f;
  }
  __syncthreads();
  for (int f = tid; f < 32 * 70; f += 256) {
    int nl = f / 70, j = f % 70;
    int gn = n0 + nl;
    if (gn >= N_NODES) continue;
    float v;
    if (j < 3) {
      v = ecb[j];
      for (int c = 0; c < H; ++c) v = fmaf(hs[nl][c], ecw[c * 3 + j], v);
    } else if (j < 67) {
      int jj = j - 3;
      v = efb[jj];
      for (int c = 0; c < H; ++c) v = fmaf(hs[nl][c], efw[c * ND + jj], v);
    } else {
      v = p[gn * 3 + (j - 67)];
    }
    out[gn * 70 + j] = v;
  }
}

// ---------------------------------------------------------------------------
extern "C" void kernel_launch(void* const* d_in, const int* in_sizes, int n_in,
                              void* d_out, int out_size, void* d_ws, size_t ws_size,
                              hipStream_t stream) {
  const float* x = (const float*)d_in[0];
  const float* pos = (const float*)d_in[1];
  const float* t = (const float*)d_in[2];
  const float* s = (const float*)d_in[3];
  const float* pw = (const float*)d_in[4];
  const float* pb = (const float*)d_in[5];
  const float* ew1 = (const float*)d_in[6];
  const float* eb1 = (const float*)d_in[7];
  const float* ew2 = (const float*)d_in[8];
  const float* eb2 = (const float*)d_in[9];
  const float* nw1 = (const float*)d_in[10];
  const float* nb1 = (const float*)d_in[11];
  const float* nw2 = (const float*)d_in[12];
  const float* nb2 = (const float*)d_in[13];
  const float* cw = (const float*)d_in[14];
  const float* cb = (const float*)d_in[15];
  const float* ecw = (const float*)d_in[16];
  const float* ecb = (const float*)d_in[17];
  const float* efw = (const float*)d_in[18];
  const float* efb = (const float*)d_in[19];

  char* wp = (char*)d_ws;
  auto alloc = [&](size_t bytes) {
    char* r = wp;
    wp += (bytes + 255) & ~(size_t)255;
    return r;
  };
  float* h0 = (float*)alloc((size_t)N_NODES * H * 4);
  float* h1 = (float*)alloc((size_t)N_NODES * H * 4);
  float* Abuf = (float*)alloc((size_t)N_NODES * H * 4);
  float* Bbuf = (float*)alloc((size_t)N_NODES * H * 4);
  float* msum = (float*)alloc((size_t)N_NODES * H * 4);
  float* p0 = (float*)alloc((size_t)N_NODES * 3 * 4);
  float* p1 = (float*)alloc((size_t)N_NODES * 3 * 4);
  float* cu = (float*)alloc((size_t)N_NODES * 3 * 4);
  int* degi = (int*)alloc((size_t)N_NODES * 4);
  int* nbr = (int*)alloc((size_t)E_EDGES * 4);
  int* off = (int*)alloc((size_t)(N_NODES + 1) * 4);
  int* cursor = (int*)alloc((size_t)N_NODES * 4);
  int* eid = (int*)alloc((size_t)E_EDGES * 4);

  // pos4 aliases msum (msum first written in layer loop, after KNN is done)
  float4* pos4 = (float4*)msum;

  hipMemsetAsync(degi, 0, (size_t)N_NODES * 4, stream);
  pos4_kernel<<<(N_NODES + 255) / 256, 256, 0, stream>>>(pos, pos4);
  knn_kernel<<<N_NODES / 4, 256, 0, stream>>>(pos4, nbr);
  deg_count_kernel<<<(E_EDGES + 255) / 256, 256, 0, stream>>>(nbr, degi);
  scan_kernel<<<1, 1024, 0, stream>>>(degi, off, cursor);
  scatter_kernel<<<(E_EDGES + 255) / 256, 256, 0, stream>>>(nbr, cursor, eid);
  sort_kernel<<<(N_NODES + 255) / 256, 256, 0, stream>>>(off, eid);
  hipMemcpyAsync(p0, pos, (size_t)N_NODES * 3 * 4, hipMemcpyDeviceToDevice, stream);
  proj_kernel<<<N_NODES / 2, 256, 0, stream>>>(x, s, t, pw, pb, h0);

  float* hc = h0;
  float* hn = h1;
  float* pc = p0;
  float* pn = p1;
  for (int l = 0; l < LAYERS; ++l) {
    const float* ew1l = ew1 + (size_t)l * 257 * H;
    ab_kernel<<<N_NODES / 16, 256, 0, stream>>>(hc, ew1l, eb1 + l * H, Abuf, Bbuf);
    edge_kernel<<<N_NODES / 4, 256, 0, stream>>>(
        Abuf, Bbuf, pc, s, off, eid, ew1l + 256 * H, ew2 + (size_t)l * H * H,
        eb2 + l * H, cw + l * H, cb + l, msum, cu);
    node_kernel<<<N_NODES / 8, 256, 0, stream>>>(
        hc, msum, degi, cu, pc, nw1 + (size_t)l * 2 * H * H, nb1 + l * H,
        nw2 + (size_t)l * H * H, nb2 + l * H, hn, pn);
    float* tmp = hc; hc = hn; hn = tmp;
    tmp = pc; pc = pn; pn = tmp;
  }
  out_kernel<<<(N_NODES + 31) / 32, 256, 0, stream>>>(hc, pc, ecw, ecb, efw, efb,
                                                      (float*)d_out);
}

// Round 4
// 839.072 us; speedup vs baseline: 5.0086x; 2.0799x over previous
//
#include <hip/hip_runtime.h>
#include <math.h>

#define N_NODES 10000
#define ND 64
#define H 128
#define LAYERS 4
#define KNN 16
#define TD 16
#define E_EDGES (N_NODES * KNN)
#define KC 2500    // knn candidates per LDS chunk
#define TILE_E 128 // edges per block in edge_mfma_kernel

typedef __attribute__((ext_vector_type(8))) short short8;
typedef __attribute__((ext_vector_type(4))) float f32x4;

__device__ __forceinline__ float silu(float x) { return x / (1.0f + __expf(-x)); }

__device__ __forceinline__ unsigned short f2bf(float f) {
  unsigned int u = __float_as_uint(f);
  u += 0x7fffu + ((u >> 16) & 1u);  // RNE
  return (unsigned short)(u >> 16);
}
__device__ __forceinline__ float bf2f(unsigned short h) {
  return __uint_as_float(((unsigned int)h) << 16);
}

// ---------------------------------------------------------------------------
// pos4 precompute: [x,y,z, x^2+y^2+z^2] per node
// ---------------------------------------------------------------------------
__global__ __launch_bounds__(256) void pos4_kernel(const float* __restrict__ pos,
                                                   float4* __restrict__ pos4) {
  int i = blockIdx.x * 256 + threadIdx.x;
  if (i >= N_NODES) return;
  float x = pos[i * 3 + 0], y = pos[i * 3 + 1], z = pos[i * 3 + 2];
  pos4[i] = make_float4(x, y, z, x * x + y * y + z * z);
}

// ---------------------------------------------------------------------------
// KNN, wave-cooperative: one query per wave; top-16 distributed in lanes 0..15.
// ---------------------------------------------------------------------------
__global__ __launch_bounds__(256) void knn_kernel(const float4* __restrict__ pos4,
                                                  int* __restrict__ nbr) {
  __shared__ float4 C[KC];
  int tid = threadIdx.x;
  int lane = tid & 63;
  int wid = tid >> 6;
  int i = blockIdx.x * 4 + wid;
  float4 q = pos4[i];
  float v = __builtin_inff();
  int vid = 0;
  float thresh = __builtin_inff();
  for (int base = 0; base < N_NODES; base += KC) {
    int cnt = min(KC, N_NODES - base);
    __syncthreads();
    for (int jj = tid; jj < cnt; jj += 256) C[jj] = pos4[base + jj];
    __syncthreads();
    for (int j0 = 0; j0 < cnt; j0 += 64) {
      int jl = j0 + lane;
      float d2 = __builtin_inff();
      if (jl < cnt) {
        float4 p = C[jl];
        d2 = q.w + p.w - 2.0f * (q.x * p.x + q.y * p.y + q.z * p.z);
        if (base + jl == i) d2 = __builtin_inff();
      }
      unsigned long long mask = __ballot(d2 < thresh);
      while (mask) {
        int sl = __ffsll((long long)mask) - 1;
        mask &= mask - 1;
        float d2b = __shfl(d2, sl, 64);
        if (d2b >= thresh) continue;
        int gjb = base + j0 + sl;
        float prevv = __shfl_up(v, 1, 64);
        int previd = __shfl_up(vid, 1, 64);
        bool stay = (v <= d2b);
        bool takenew = (lane == 0) || (prevv <= d2b);
        v = stay ? v : (takenew ? d2b : prevv);
        vid = stay ? vid : (takenew ? gjb : previd);
        thresh = __shfl(v, 15, 64);
      }
    }
  }
  if (lane < KNN) nbr[i * KNN + lane] = vid;
}

// ---------------------------------------------------------------------------
// CSR build (deterministic): count -> scan -> scatter(+dstof) -> per-node sort
// ---------------------------------------------------------------------------
__global__ void deg_count_kernel(const int* __restrict__ nbr, int* __restrict__ degi) {
  int e = blockIdx.x * 256 + threadIdx.x;
  if (e < E_EDGES) atomicAdd(&degi[nbr[e]], 1);
}

__global__ __launch_bounds__(1024) void scan_kernel(const int* __restrict__ degi,
                                                    int* __restrict__ off,
                                                    int* __restrict__ cursor) {
  __shared__ int part[1024];
  int t = threadIdx.x;
  int base = t * 10;
  int sum = 0;
  if (t < 1000)
    for (int i = 0; i < 10; ++i) sum += degi[base + i];
  part[t] = sum;
  __syncthreads();
  for (int stp = 1; stp < 1024; stp <<= 1) {
    int v = (t >= stp) ? part[t - stp] : 0;
    __syncthreads();
    part[t] += v;
    __syncthreads();
  }
  if (t < 1000) {
    int run = (t == 0) ? 0 : part[t - 1];
    for (int i = 0; i < 10; ++i) {
      off[base + i] = run;
      cursor[base + i] = run;
      run += degi[base + i];
    }
  }
  if (t == 0) off[N_NODES] = E_EDGES;
}

__global__ void scatter_kernel(const int* __restrict__ nbr, int* __restrict__ cursor,
                               int* __restrict__ eid, int* __restrict__ dstof) {
  int e = blockIdx.x * 256 + threadIdx.x;
  if (e < E_EDGES) {
    int d = nbr[e];
    int p = atomicAdd(&cursor[d], 1);
    eid[p] = e;
    dstof[p] = d;
  }
}

__global__ void sort_kernel(const int* __restrict__ off, int* __restrict__ eid) {
  int n = blockIdx.x * 256 + threadIdx.x;
  if (n >= N_NODES) return;
  int a = off[n], b = off[n + 1];
  for (int i = a + 1; i < b; ++i) {
    int v = eid[i];
    int j = i - 1;
    while (j >= a && eid[j] > v) { eid[j + 1] = eid[j]; --j; }
    eid[j + 1] = v;
  }
}

// ---------------------------------------------------------------------------
// Input projection
// ---------------------------------------------------------------------------
__global__ __launch_bounds__(256) void proj_kernel(const float* __restrict__ x,
                                                   const float* __restrict__ s,
                                                   const float* __restrict__ tptr,
                                                   const float* __restrict__ pw,
                                                   const float* __restrict__ pb,
                                                   float* __restrict__ h) {
  __shared__ float inp[2][81];
  int tid = threadIdx.x;
  int g = tid >> 7;
  int o = tid & 127;
  int node = blockIdx.x * 2 + g;
  float t = tptr[0];
  if (o < 64) inp[g][o] = x[node * ND + o];
  else if (o == 64) inp[g][64] = s[node];
  else if (o < 81) {
    int j = o - 65;
    int jj = (j < 8) ? j : (j - 8);
    float f = __expf(-4.0f * (float)jj / 7.0f);
    float a = t * f;
    inp[g][o] = (j < 8) ? sinf(a) : cosf(a);
  }
  __syncthreads();
  float acc = pb[o];
#pragma unroll
  for (int c = 0; c < 81; ++c) acc = fmaf(inp[g][c], pw[c * H + o], acc);
  h[node * H + o] = acc;
}

// ---------------------------------------------------------------------------
// A = h @ ew1[0:128] + eb1 ; B = h @ ew1[128:256].  16 nodes per block.
// ---------------------------------------------------------------------------
__global__ __launch_bounds__(256) void ab_kernel(const float* __restrict__ h,
                                                 const float* __restrict__ ew1,
                                                 const float* __restrict__ eb1,
                                                 float* __restrict__ A,
                                                 float* __restrict__ B) {
  __shared__ float hs[16][H];
  int tid = threadIdx.x;
  int n0 = blockIdx.x * 16;
  for (int idx = tid; idx < 16 * H; idx += 256) {
    int n = idx >> 7, c = idx & 127;
    hs[n][c] = h[(n0 + n) * H + c];
  }
  __syncthreads();
  int part = tid >> 7, o = tid & 127;
  const float* W = ew1 + part * H * H;
  float acc[16];
#pragma unroll
  for (int n = 0; n < 16; ++n) acc[n] = 0.0f;
  for (int c = 0; c < H; c += 4) {
    float4 wv;
    wv.x = W[(c + 0) * H + o];
    wv.y = W[(c + 1) * H + o];
    wv.z = W[(c + 2) * H + o];
    wv.w = W[(c + 3) * H + o];
#pragma unroll
    for (int n = 0; n < 16; ++n) {
      float4 hv = *(const float4*)&hs[n][c];
      acc[n] = fmaf(hv.x, wv.x, acc[n]);
      acc[n] = fmaf(hv.y, wv.y, acc[n]);
      acc[n] = fmaf(hv.z, wv.z, acc[n]);
      acc[n] = fmaf(hv.w, wv.w, acc[n]);
    }
  }
  float bias = (part == 0) ? eb1[o] : 0.0f;
  float* out = (part == 0) ? A : B;
#pragma unroll
  for (int n = 0; n < 16; ++n) out[(n0 + n) * H + o] = acc[n] + bias;
}

// ---------------------------------------------------------------------------
// Edge phase, MFMA: 128 CSR positions per block.
//  t1 = silu(A[dst]+B[src]+r2*wr) -> bf16 LDS (136-elem padded rows)
//  m  = silu(t1 @ w2 + b2) * s[src]  via mfma_f32_16x16x32_bf16
//  gamma = m @ cw + cb ; per-node partial msum/cu -> two-slot global buffers:
//  slot A = tile that STARTS the node (zeroes slot B if node ends here too),
//  slot B = continuation tile. Valid for deg <= 129 (KNN in-degree << that).
//  deg-0 nodes are never written (node_kernel guards deg>0).
// ---------------------------------------------------------------------------
__global__ __launch_bounds__(256) void edge_mfma_kernel(
    const float* __restrict__ A, const float* __restrict__ Bm,
    const float* __restrict__ p, const float* __restrict__ s,
    const int* __restrict__ csr_off, const int* __restrict__ eid,
    const int* __restrict__ dstof, const float* __restrict__ wr,
    const float* __restrict__ ew2, const float* __restrict__ eb2,
    const float* __restrict__ cw, const float* __restrict__ cbp,
    float* __restrict__ msA, float* __restrict__ msB,
    float* __restrict__ cuA, float* __restrict__ cuB) {
  __shared__ unsigned short t1s[TILE_E][136];  // t1 (bf16), later reused for m
  __shared__ unsigned short w2T[H][136];       // w2 transposed [out][in] (bf16)
  __shared__ float r2A[TILE_E], sA[TILE_E], dirA[TILE_E][3], gA[TILE_E];
  __shared__ int srcA[TILE_E], dstA[TILE_E];
  __shared__ float wrs[H], b2s[H], cws[H];

  int tid = threadIdx.x;
  int P0 = blockIdx.x * TILE_E;
  int P1 = P0 + TILE_E;

  // stage 0: weights to LDS (w2 transposed, bf16)
  for (int idx = tid; idx < H * H; idx += 256) {
    int c = idx >> 7, o = idx & 127;
    w2T[o][c] = f2bf(ew2[idx]);
  }
  if (tid < H) { wrs[tid] = wr[tid]; b2s[tid] = eb2[tid]; cws[tid] = cw[tid]; }
  // stage 0b: per-edge geometry
  if (tid < TILE_E) {
    int e = tid;
    int edge = eid[P0 + e];
    int src = edge >> 4;  // edge / KNN
    int d = dstof[P0 + e];
    srcA[e] = src;
    dstA[e] = d;
    float dx = p[d * 3 + 0] - p[src * 3 + 0];
    float dy = p[d * 3 + 1] - p[src * 3 + 1];
    float dz = p[d * 3 + 2] - p[src * 3 + 2];
    float r2 = dx * dx + dy * dy + dz * dz;
    r2A[e] = r2;
    float rinv = 1.0f / sqrtf(r2 + 1e-8f);
    dirA[e][0] = dx * rinv;
    dirA[e][1] = dy * rinv;
    dirA[e][2] = dz * rinv;
    sA[e] = s[src];
  }
  __syncthreads();

  int nA = dstA[0], nB = dstA[TILE_E - 1];
  int nn = nB - nA + 1;

  // stage 1: t1 tile (bf16), 2 cols per thread per iter, coalesced gathers
  for (int idx = tid; idx < TILE_E * 64; idx += 256) {
    int e = idx >> 6, cp = (idx & 63) * 2;
    float2 av = *(const float2*)&A[dstA[e] * H + cp];
    float2 bv = *(const float2*)&Bm[srcA[e] * H + cp];
    float r2v = r2A[e];
    float pre0 = silu(av.x + bv.x + r2v * wrs[cp]);
    float pre1 = silu(av.y + bv.y + r2v * wrs[cp + 1]);
    unsigned int u = ((unsigned int)f2bf(pre1) << 16) | (unsigned int)f2bf(pre0);
    *(unsigned int*)&t1s[e][cp] = u;
  }
  __syncthreads();

  // stage 2: GEMM m_pre = t1 @ w2. Wave w -> out cols [w*32, w*32+32).
  int w = tid >> 6, lane = tid & 63;
  int fr = lane & 15, kg = lane >> 4;
  f32x4 acc[8][2];
#pragma unroll
  for (int mt = 0; mt < 8; ++mt)
#pragma unroll
    for (int nt = 0; nt < 2; ++nt) acc[mt][nt] = (f32x4){0.f, 0.f, 0.f, 0.f};
#pragma unroll
  for (int ks = 0; ks < 4; ++ks) {
    int k = ks * 32 + kg * 8;
    short8 bf0 = *(const short8*)&w2T[w * 32 + fr][k];
    short8 bf1 = *(const short8*)&w2T[w * 32 + 16 + fr][k];
#pragma unroll
    for (int mt = 0; mt < 8; ++mt) {
      short8 a = *(const short8*)&t1s[mt * 16 + fr][k];
      acc[mt][0] = __builtin_amdgcn_mfma_f32_16x16x32_bf16(a, bf0, acc[mt][0], 0, 0, 0);
      acc[mt][1] = __builtin_amdgcn_mfma_f32_16x16x32_bf16(a, bf1, acc[mt][1], 0, 0, 0);
    }
  }
  __syncthreads();  // all t1s reads done

  // epilogue: m = silu(acc + b2) * s[src] -> back into t1s (bf16)
#pragma unroll
  for (int mt = 0; mt < 8; ++mt) {
#pragma unroll
    for (int nt = 0; nt < 2; ++nt) {
      int col = w * 32 + nt * 16 + fr;
      float b2v = b2s[col];
#pragma unroll
      for (int r = 0; r < 4; ++r) {
        int row = mt * 16 + kg * 4 + r;
        float mv = silu(acc[mt][nt][r] + b2v) * sA[row];
        t1s[row][col] = f2bf(mv);
      }
    }
  }
  __syncthreads();

  // gamma per edge (ascending col order)
  if (tid < TILE_E) {
    float g = 0.f;
    for (int c = 0; c < H; c += 2) {
      unsigned int u = *(const unsigned int*)&t1s[tid][c];
      g = fmaf(bf2f((unsigned short)(u & 0xffffu)), cws[c], g);
      g = fmaf(bf2f((unsigned short)(u >> 16)), cws[c + 1], g);
    }
    gA[tid] = g + cbp[0];
  }
  __syncthreads();

  // per-node partial msum -> slots
  for (int idx = tid; idx < nn * H; idx += 256) {
    int ni = idx >> 7, c = idx & 127;
    int n = nA + ni;
    int o0 = csr_off[n], o1 = csr_off[n + 1];
    int lo = max(o0, P0), hi = min(o1, P1);
    float sum = 0.f;
    for (int pos = lo; pos < hi; ++pos) sum += bf2f(t1s[pos - P0][c]);
    if (o0 >= P0) {
      msA[n * H + c] = sum;
      if (o1 <= P1) msB[n * H + c] = 0.0f;
    } else {
      msB[n * H + c] = sum;
    }
  }
  // per-node partial cu -> slots
  for (int idx = tid; idx < nn * 3; idx += 256) {
    int ni = idx / 3, comp = idx - ni * 3;
    int n = nA + ni;
    int o0 = csr_off[n], o1 = csr_off[n + 1];
    int lo = max(o0, P0), hi = min(o1, P1);
    float sum = 0.f;
    for (int pos = lo; pos < hi; ++pos)
      sum += gA[pos - P0] * dirA[pos - P0][comp];
    if (o0 >= P0) {
      cuA[n * 3 + comp] = sum;
      if (o1 <= P1) cuB[n * 3 + comp] = 0.0f;
    } else {
      cuB[n * 3 + comp] = sum;
    }
  }
}

// ---------------------------------------------------------------------------
// Node update: h_new = silu(cat(h, msum/deg) @ nw1 + nb1) @ nw2 + nb2
// p_new = p + (cuA+cuB)/deg.  8 nodes per block.
// ---------------------------------------------------------------------------
__global__ __launch_bounds__(256) void node_kernel(
    const float* __restrict__ h, const float* __restrict__ msA,
    const float* __restrict__ msB, const int* __restrict__ degi,
    const float* __restrict__ cuA, const float* __restrict__ cuB,
    const float* __restrict__ p_in, const float* __restrict__ nw1,
    const float* __restrict__ nb1, const float* __restrict__ nw2,
    const float* __restrict__ nb2, float* __restrict__ h_out,
    float* __restrict__ p_out) {
  __shared__ float ins[8][2 * H];
  __shared__ float hns[8][H];
  int tid = threadIdx.x;
  int n0 = blockIdx.x * 8;
  for (int idx = tid; idx < 8 * 2 * H; idx += 256) {
    int n = idx >> 8, c = idx & 255;
    int gn = n0 + n;
    float v;
    if (c < H) {
      v = h[gn * H + c];
    } else {
      int dg = degi[gn];
      v = 0.0f;
      if (dg > 0)
        v = (msA[gn * H + (c - H)] + msB[gn * H + (c - H)]) / (float)dg;
    }
    ins[n][c] = v;
  }
  __syncthreads();
  int o = tid & 127, ng = (tid >> 7) * 4;
  float acc[4];
#pragma unroll
  for (int n = 0; n < 4; ++n) acc[n] = nb1[o];
  for (int c = 0; c < 2 * H; c += 4) {
    float4 wv;
    wv.x = nw1[(c + 0) * H + o];
    wv.y = nw1[(c + 1) * H + o];
    wv.z = nw1[(c + 2) * H + o];
    wv.w = nw1[(c + 3) * H + o];
#pragma unroll
    for (int n = 0; n < 4; ++n) {
      float4 hv = *(const float4*)&ins[ng + n][c];
      acc[n] = fmaf(hv.x, wv.x, acc[n]);
      acc[n] = fmaf(hv.y, wv.y, acc[n]);
      acc[n] = fmaf(hv.z, wv.z, acc[n]);
      acc[n] = fmaf(hv.w, wv.w, acc[n]);
    }
  }
#pragma unroll
  for (int n = 0; n < 4; ++n) hns[ng + n][o] = silu(acc[n]);
  __syncthreads();
  float acc2[4];
#pragma unroll
  for (int n = 0; n < 4; ++n) acc2[n] = nb2[o];
  for (int c = 0; c < H; c += 4) {
    float4 wv;
    wv.x = nw2[(c + 0) * H + o];
    wv.y = nw2[(c + 1) * H + o];
    wv.z = nw2[(c + 2) * H + o];
    wv.w = nw2[(c + 3) * H + o];
#pragma unroll
    for (int n = 0; n < 4; ++n) {
      float4 hv = *(const float4*)&hns[ng + n][c];
      acc2[n] = fmaf(hv.x, wv.x, acc2[n]);
      acc2[n] = fmaf(hv.y, wv.y, acc2[n]);
      acc2[n] = fmaf(hv.z, wv.z, acc2[n]);
      acc2[n] = fmaf(hv.w, wv.w, acc2[n]);
    }
  }
#pragma unroll
  for (int n = 0; n < 4; ++n) h_out[(n0 + ng + n) * H + o] = acc2[n];
  if (tid < 24) {
    int nl = tid / 3, comp = tid - nl * 3;
    int gn = n0 + nl;
    int dg = degi[gn];
    float add = 0.0f;
    if (dg > 0)
      add = (cuA[gn * 3 + comp] + cuB[gn * 3 + comp]) / (float)dg;
    p_out[gn * 3 + comp] = p_in[gn * 3 + comp] + add;
  }
}

// ---------------------------------------------------------------------------
// Output head
// ---------------------------------------------------------------------------
__global__ __launch_bounds__(256) void out_kernel(
    const float* __restrict__ h, const float* __restrict__ p,
    const float* __restrict__ ecw, const float* __restrict__ ecb,
    const float* __restrict__ efw, const float* __restrict__ efb,
    float* __restrict__ out) {
  __shared__ float hs[32][H];
  int tid = threadIdx.x, n0 = blockIdx.x * 32;
  for (int idx = tid; idx < 32 * H; idx += 256) {
    int n = idx >> 7, c = idx & 127;
    int gn = n0 + n;
    hs[n][c] = (gn < N_NODES) ? h[gn * H + c] : 0.0f;
  }
  __syncthreads();
  for (int f = tid; f < 32 * 70; f += 256) {
    int nl = f / 70, j = f % 70;
    int gn = n0 + nl;
    if (gn >= N_NODES) continue;
    float v;
    if (j < 3) {
      v = ecb[j];
      for (int c = 0; c < H; ++c) v = fmaf(hs[nl][c], ecw[c * 3 + j], v);
    } else if (j < 67) {
      int jj = j - 3;
      v = efb[jj];
      for (int c = 0; c < H; ++c) v = fmaf(hs[nl][c], efw[c * ND + jj], v);
    } else {
      v = p[gn * 3 + (j - 67)];
    }
    out[gn * 70 + j] = v;
  }
}

// ---------------------------------------------------------------------------
extern "C" void kernel_launch(void* const* d_in, const int* in_sizes, int n_in,
                              void* d_out, int out_size, void* d_ws, size_t ws_size,
                              hipStream_t stream) {
  const float* x = (const float*)d_in[0];
  const float* pos = (const float*)d_in[1];
  const float* t = (const float*)d_in[2];
  const float* s = (const float*)d_in[3];
  const float* pw = (const float*)d_in[4];
  const float* pb = (const float*)d_in[5];
  const float* ew1 = (const float*)d_in[6];
  const float* eb1 = (const float*)d_in[7];
  const float* ew2 = (const float*)d_in[8];
  const float* eb2 = (const float*)d_in[9];
  const float* nw1 = (const float*)d_in[10];
  const float* nb1 = (const float*)d_in[11];
  const float* nw2 = (const float*)d_in[12];
  const float* nb2 = (const float*)d_in[13];
  const float* cw = (const float*)d_in[14];
  const float* cb = (const float*)d_in[15];
  const float* ecw = (const float*)d_in[16];
  const float* ecb = (const float*)d_in[17];
  const float* efw = (const float*)d_in[18];
  const float* efb = (const float*)d_in[19];

  char* wp = (char*)d_ws;
  auto alloc = [&](size_t bytes) {
    char* r = wp;
    wp += (bytes + 255) & ~(size_t)255;
    return r;
  };
  float* h0 = (float*)alloc((size_t)N_NODES * H * 4);
  float* h1 = (float*)alloc((size_t)N_NODES * H * 4);
  float* Abuf = (float*)alloc((size_t)N_NODES * H * 4);
  float* Bbuf = (float*)alloc((size_t)N_NODES * H * 4);
  float* msAb = (float*)alloc((size_t)N_NODES * H * 4);
  float* msBb = (float*)alloc((size_t)N_NODES * H * 4);
  float* cuAb = (float*)alloc((size_t)N_NODES * 3 * 4);
  float* cuBb = (float*)alloc((size_t)N_NODES * 3 * 4);
  float* p0 = (float*)alloc((size_t)N_NODES * 3 * 4);
  float* p1 = (float*)alloc((size_t)N_NODES * 3 * 4);
  int* degi = (int*)alloc((size_t)N_NODES * 4);
  int* nbr = (int*)alloc((size_t)E_EDGES * 4);
  int* off = (int*)alloc((size_t)(N_NODES + 1) * 4);
  int* cursor = (int*)alloc((size_t)N_NODES * 4);
  int* eid = (int*)alloc((size_t)E_EDGES * 4);
  int* dstof = (int*)alloc((size_t)E_EDGES * 4);

  // pos4 aliases msAb (first written by edge_mfma, after KNN is done)
  float4* pos4 = (float4*)msAb;

  hipMemsetAsync(degi, 0, (size_t)N_NODES * 4, stream);
  pos4_kernel<<<(N_NODES + 255) / 256, 256, 0, stream>>>(pos, pos4);
  knn_kernel<<<N_NODES / 4, 256, 0, stream>>>(pos4, nbr);
  deg_count_kernel<<<(E_EDGES + 255) / 256, 256, 0, stream>>>(nbr, degi);
  scan_kernel<<<1, 1024, 0, stream>>>(degi, off, cursor);
  scatter_kernel<<<(E_EDGES + 255) / 256, 256, 0, stream>>>(nbr, cursor, eid, dstof);
  sort_kernel<<<(N_NODES + 255) / 256, 256, 0, stream>>>(off, eid);
  hipMemcpyAsync(p0, pos, (size_t)N_NODES * 3 * 4, hipMemcpyDeviceToDevice, stream);
  proj_kernel<<<N_NODES / 2, 256, 0, stream>>>(x, s, t, pw, pb, h0);

  float* hc = h0;
  float* hn = h1;
  float* pc = p0;
  float* pn = p1;
  for (int l = 0; l < LAYERS; ++l) {
    const float* ew1l = ew1 + (size_t)l * 257 * H;
    ab_kernel<<<N_NODES / 16, 256, 0, stream>>>(hc, ew1l, eb1 + l * H, Abuf, Bbuf);
    edge_mfma_kernel<<<E_EDGES / TILE_E, 256, 0, stream>>>(
        Abuf, Bbuf, pc, s, off, eid, dstof, ew1l + 256 * H,
        ew2 + (size_t)l * H * H, eb2 + l * H, cw + l * H, cb + l,
        msAb, msBb, cuAb, cuBb);
    node_kernel<<<N_NODES / 8, 256, 0, stream>>>(
        hc, msAb, msBb, degi, cuAb, cuBb, pc, nw1 + (size_t)l * 2 * H * H,
        nb1 + l * H, nw2 + (size_t)l * H * H, nb2 + l * H, hn, pn);
    float* tmp = hc; hc = hn; hn = tmp;
    tmp = pc; pc = pn; pn = tmp;
  }
  out_kernel<<<(N_NODES + 31) / 32, 256, 0, stream>>>(hc, pc, ecw, ecb, efw, efb,
                                                      (float*)d_out);
}

// Round 5
// 655.102 us; speedup vs baseline: 6.4151x; 1.2808x over previous
//
#include <hip/hip_runtime.h>
#include <math.h>

#define N_NODES 10000
#define ND 64
#define H 128
#define LAYERS 4
#define KNN 16
#define TD 16
#define E_EDGES (N_NODES * KNN)
#define KC 1250    // knn candidates per LDS chunk (20 KB -> ~8 blocks/CU)
#define TILE_E 128 // edges per block in edge_mfma_kernel

typedef __attribute__((ext_vector_type(8))) short short8;
typedef __attribute__((ext_vector_type(4))) float f32x4;

__device__ __forceinline__ float silu(float x) { return x / (1.0f + __expf(-x)); }

__device__ __forceinline__ unsigned short f2bf(float f) {
  unsigned int u = __float_as_uint(f);
  u += 0x7fffu + ((u >> 16) & 1u);  // RNE
  return (unsigned short)(u >> 16);
}
__device__ __forceinline__ float bf2f(unsigned short h) {
  return __uint_as_float(((unsigned int)h) << 16);
}

// ---------------------------------------------------------------------------
// pos4 precompute: [x,y,z, x^2+y^2+z^2] per node
// ---------------------------------------------------------------------------
__global__ __launch_bounds__(256) void pos4_kernel(const float* __restrict__ pos,
                                                   float4* __restrict__ pos4) {
  int i = blockIdx.x * 256 + threadIdx.x;
  if (i >= N_NODES) return;
  float x = pos[i * 3 + 0], y = pos[i * 3 + 1], z = pos[i * 3 + 2];
  pos4[i] = make_float4(x, y, z, x * x + y * y + z * z);
}

// ---------------------------------------------------------------------------
// Weight precast: bf16 transposed copies of ew2, nw1, nw2 ([l][out][in]).
// ---------------------------------------------------------------------------
__global__ __launch_bounds__(256) void wcvt_kernel(
    const float* __restrict__ ew2, const float* __restrict__ nw1,
    const float* __restrict__ nw2, unsigned short* __restrict__ w2T,
    unsigned short* __restrict__ nw1T, unsigned short* __restrict__ nw2T) {
  int i = blockIdx.x * 256 + threadIdx.x;  // 262144 total
  if (i < 65536) {  // w2T: [l][o][c] <- ew2[l][c][o]
    int l = i >> 14, rem = i & 16383, o = rem >> 7, c = rem & 127;
    w2T[i] = f2bf(ew2[l * 16384 + c * 128 + o]);
  } else if (i < 196608) {  // nw1T: [l][o][c2] <- nw1[l][c2][o]
    int j = i - 65536;
    int l = j >> 15, rem = j & 32767, o = rem >> 8, c2 = rem & 255;
    nw1T[j] = f2bf(nw1[l * 32768 + c2 * 128 + o]);
  } else {  // nw2T: [l][o][c] <- nw2[l][c][o]
    int j = i - 196608;
    int l = j >> 14, rem = j & 16383, o = rem >> 7, c = rem & 127;
    nw2T[j] = f2bf(nw2[l * 16384 + c * 128 + o]);
  }
}

// ---------------------------------------------------------------------------
// KNN, wave-cooperative: one query per wave; top-16 distributed in lanes 0..15.
// ---------------------------------------------------------------------------
__global__ __launch_bounds__(256) void knn_kernel(const float4* __restrict__ pos4,
                                                  int* __restrict__ nbr) {
  __shared__ float4 C[KC];
  int tid = threadIdx.x;
  int lane = tid & 63;
  int wid = tid >> 6;
  int i = blockIdx.x * 4 + wid;
  float4 q = pos4[i];
  float v = __builtin_inff();
  int vid = 0;
  float thresh = __builtin_inff();
  for (int base = 0; base < N_NODES; base += KC) {
    int cnt = min(KC, N_NODES - base);
    __syncthreads();
    for (int jj = tid; jj < cnt; jj += 256) C[jj] = pos4[base + jj];
    __syncthreads();
    for (int j0 = 0; j0 < cnt; j0 += 64) {
      int jl = j0 + lane;
      float d2 = __builtin_inff();
      if (jl < cnt) {
        float4 p = C[jl];
        d2 = q.w + p.w - 2.0f * (q.x * p.x + q.y * p.y + q.z * p.z);
        if (base + jl == i) d2 = __builtin_inff();
      }
      unsigned long long mask = __ballot(d2 < thresh);
      while (mask) {
        int sl = __ffsll((long long)mask) - 1;
        mask &= mask - 1;
        float d2b = __shfl(d2, sl, 64);
        if (d2b >= thresh) continue;
        int gjb = base + j0 + sl;
        float prevv = __shfl_up(v, 1, 64);
        int previd = __shfl_up(vid, 1, 64);
        bool stay = (v <= d2b);
        bool takenew = (lane == 0) || (prevv <= d2b);
        v = stay ? v : (takenew ? d2b : prevv);
        vid = stay ? vid : (takenew ? gjb : previd);
        thresh = __shfl(v, 15, 64);
      }
    }
  }
  if (lane < KNN) nbr[i * KNN + lane] = vid;
}

// ---------------------------------------------------------------------------
// CSR build (deterministic): count -> scan -> scatter(+dstof) -> per-node sort
// ---------------------------------------------------------------------------
__global__ void deg_count_kernel(const int* __restrict__ nbr, int* __restrict__ degi) {
  int e = blockIdx.x * 256 + threadIdx.x;
  if (e < E_EDGES) atomicAdd(&degi[nbr[e]], 1);
}

__global__ __launch_bounds__(1024) void scan_kernel(const int* __restrict__ degi,
                                                    int* __restrict__ off,
                                                    int* __restrict__ cursor) {
  __shared__ int part[1024];
  int t = threadIdx.x;
  int base = t * 10;
  int sum = 0;
  if (t < 1000)
    for (int i = 0; i < 10; ++i) sum += degi[base + i];
  part[t] = sum;
  __syncthreads();
  for (int stp = 1; stp < 1024; stp <<= 1) {
    int v = (t >= stp) ? part[t - stp] : 0;
    __syncthreads();
    part[t] += v;
    __syncthreads();
  }
  if (t < 1000) {
    int run = (t == 0) ? 0 : part[t - 1];
    for (int i = 0; i < 10; ++i) {
      off[base + i] = run;
      cursor[base + i] = run;
      run += degi[base + i];
    }
  }
  if (t == 0) off[N_NODES] = E_EDGES;
}

__global__ void scatter_kernel(const int* __restrict__ nbr, int* __restrict__ cursor,
                               int* __restrict__ eid, int* __restrict__ dstof) {
  int e = blockIdx.x * 256 + threadIdx.x;
  if (e < E_EDGES) {
    int d = nbr[e];
    int p = atomicAdd(&cursor[d], 1);
    eid[p] = e;
    dstof[p] = d;
  }
}

__global__ void sort_kernel(const int* __restrict__ off, int* __restrict__ eid) {
  int n = blockIdx.x * 256 + threadIdx.x;
  if (n >= N_NODES) return;
  int a = off[n], b = off[n + 1];
  for (int i = a + 1; i < b; ++i) {
    int v = eid[i];
    int j = i - 1;
    while (j >= a && eid[j] > v) { eid[j + 1] = eid[j]; --j; }
    eid[j + 1] = v;
  }
}

// ---------------------------------------------------------------------------
// Input projection
// ---------------------------------------------------------------------------
__global__ __launch_bounds__(256) void proj_kernel(const float* __restrict__ x,
                                                   const float* __restrict__ s,
                                                   const float* __restrict__ tptr,
                                                   const float* __restrict__ pw,
                                                   const float* __restrict__ pb,
                                                   float* __restrict__ h) {
  __shared__ float inp[2][81];
  int tid = threadIdx.x;
  int g = tid >> 7;
  int o = tid & 127;
  int node = blockIdx.x * 2 + g;
  float t = tptr[0];
  if (o < 64) inp[g][o] = x[node * ND + o];
  else if (o == 64) inp[g][64] = s[node];
  else if (o < 81) {
    int j = o - 65;
    int jj = (j < 8) ? j : (j - 8);
    float f = __expf(-4.0f * (float)jj / 7.0f);
    float a = t * f;
    inp[g][o] = (j < 8) ? sinf(a) : cosf(a);
  }
  __syncthreads();
  float acc = pb[o];
#pragma unroll
  for (int c = 0; c < 81; ++c) acc = fmaf(inp[g][c], pw[c * H + o], acc);
  h[node * H + o] = acc;
}

// ---------------------------------------------------------------------------
// A = h @ ew1[0:128] + eb1 ; B = h @ ew1[128:256].  16 nodes per block.
// ---------------------------------------------------------------------------
__global__ __launch_bounds__(256) void ab_kernel(const float* __restrict__ h,
                                                 const float* __restrict__ ew1,
                                                 const float* __restrict__ eb1,
                                                 float* __restrict__ A,
                                                 float* __restrict__ B) {
  __shared__ float hs[16][H];
  int tid = threadIdx.x;
  int n0 = blockIdx.x * 16;
  for (int idx = tid; idx < 16 * H; idx += 256) {
    int n = idx >> 7, c = idx & 127;
    hs[n][c] = h[(n0 + n) * H + c];
  }
  __syncthreads();
  int part = tid >> 7, o = tid & 127;
  const float* W = ew1 + part * H * H;
  float acc[16];
#pragma unroll
  for (int n = 0; n < 16; ++n) acc[n] = 0.0f;
  for (int c = 0; c < H; c += 4) {
    float4 wv;
    wv.x = W[(c + 0) * H + o];
    wv.y = W[(c + 1) * H + o];
    wv.z = W[(c + 2) * H + o];
    wv.w = W[(c + 3) * H + o];
#pragma unroll
    for (int n = 0; n < 16; ++n) {
      float4 hv = *(const float4*)&hs[n][c];
      acc[n] = fmaf(hv.x, wv.x, acc[n]);
      acc[n] = fmaf(hv.y, wv.y, acc[n]);
      acc[n] = fmaf(hv.z, wv.z, acc[n]);
      acc[n] = fmaf(hv.w, wv.w, acc[n]);
    }
  }
  float bias = (part == 0) ? eb1[o] : 0.0f;
  float* out = (part == 0) ? A : B;
#pragma unroll
  for (int n = 0; n < 16; ++n) out[(n0 + n) * H + o] = acc[n] + bias;
}

// ---------------------------------------------------------------------------
// Edge phase, MFMA: 128 CSR positions per block. B-frags from global bf16 w2T.
// ---------------------------------------------------------------------------
__global__ __launch_bounds__(256) void edge_mfma_kernel(
    const float* __restrict__ A, const float* __restrict__ Bm,
    const float* __restrict__ p, const float* __restrict__ s,
    const int* __restrict__ csr_off, const int* __restrict__ eid,
    const int* __restrict__ dstof, const float* __restrict__ wr,
    const unsigned short* __restrict__ w2T, const float* __restrict__ eb2,
    const float* __restrict__ cw, const float* __restrict__ cbp,
    float* __restrict__ msA, float* __restrict__ msB,
    float* __restrict__ cuA, float* __restrict__ cuB) {
  __shared__ unsigned short t1s[TILE_E][136];  // t1 (bf16), later reused for m
  __shared__ float r2A[TILE_E], sA[TILE_E], dirA[TILE_E][3], gA[TILE_E];
  __shared__ int srcA[TILE_E], dstA[TILE_E];
  __shared__ float wrs[H], b2s[H], cws[H];

  int tid = threadIdx.x;
  int P0 = blockIdx.x * TILE_E;
  int P1 = P0 + TILE_E;

  if (tid < H) { wrs[tid] = wr[tid]; b2s[tid] = eb2[tid]; cws[tid] = cw[tid]; }
  // per-edge geometry
  if (tid < TILE_E) {
    int e = tid;
    int edge = eid[P0 + e];
    int src = edge >> 4;  // edge / KNN
    int d = dstof[P0 + e];
    srcA[e] = src;
    dstA[e] = d;
    float dx = p[d * 3 + 0] - p[src * 3 + 0];
    float dy = p[d * 3 + 1] - p[src * 3 + 1];
    float dz = p[d * 3 + 2] - p[src * 3 + 2];
    float r2 = dx * dx + dy * dy + dz * dz;
    r2A[e] = r2;
    float rinv = 1.0f / sqrtf(r2 + 1e-8f);
    dirA[e][0] = dx * rinv;
    dirA[e][1] = dy * rinv;
    dirA[e][2] = dz * rinv;
    sA[e] = s[src];
  }
  __syncthreads();

  int nA = dstA[0], nB = dstA[TILE_E - 1];
  int nn = nB - nA + 1;

  // stage 1: t1 tile (bf16)
  for (int idx = tid; idx < TILE_E * 64; idx += 256) {
    int e = idx >> 6, cp = (idx & 63) * 2;
    float2 av = *(const float2*)&A[dstA[e] * H + cp];
    float2 bv = *(const float2*)&Bm[srcA[e] * H + cp];
    float r2v = r2A[e];
    float pre0 = silu(av.x + bv.x + r2v * wrs[cp]);
    float pre1 = silu(av.y + bv.y + r2v * wrs[cp + 1]);
    unsigned int u = ((unsigned int)f2bf(pre1) << 16) | (unsigned int)f2bf(pre0);
    *(unsigned int*)&t1s[e][cp] = u;
  }
  __syncthreads();

  // stage 2: GEMM m_pre = t1 @ w2. Wave w -> out cols [w*32, w*32+32).
  int w = tid >> 6, lane = tid & 63;
  int fr = lane & 15, kg = lane >> 4;
  f32x4 acc[8][2];
#pragma unroll
  for (int mt = 0; mt < 8; ++mt)
#pragma unroll
    for (int nt = 0; nt < 2; ++nt) acc[mt][nt] = (f32x4){0.f, 0.f, 0.f, 0.f};
#pragma unroll
  for (int ks = 0; ks < 4; ++ks) {
    int k = ks * 32 + kg * 8;
    short8 bf0 = *(const short8*)&w2T[(w * 32 + fr) * H + k];
    short8 bf1 = *(const short8*)&w2T[(w * 32 + 16 + fr) * H + k];
#pragma unroll
    for (int mt = 0; mt < 8; ++mt) {
      short8 a = *(const short8*)&t1s[mt * 16 + fr][k];
      acc[mt][0] = __builtin_amdgcn_mfma_f32_16x16x32_bf16(a, bf0, acc[mt][0], 0, 0, 0);
      acc[mt][1] = __builtin_amdgcn_mfma_f32_16x16x32_bf16(a, bf1, acc[mt][1], 0, 0, 0);
    }
  }
  __syncthreads();  // all t1s reads done

  // epilogue: m = silu(acc + b2) * s[src] -> back into t1s (bf16)
#pragma unroll
  for (int mt = 0; mt < 8; ++mt) {
#pragma unroll
    for (int nt = 0; nt < 2; ++nt) {
      int col = w * 32 + nt * 16 + fr;
      float b2v = b2s[col];
#pragma unroll
      for (int r = 0; r < 4; ++r) {
        int row = mt * 16 + kg * 4 + r;
        float mv = silu(acc[mt][nt][r] + b2v) * sA[row];
        t1s[row][col] = f2bf(mv);
      }
    }
  }
  __syncthreads();

  // gamma per edge (ascending col order)
  if (tid < TILE_E) {
    float g = 0.f;
    for (int c = 0; c < H; c += 2) {
      unsigned int u = *(const unsigned int*)&t1s[tid][c];
      g = fmaf(bf2f((unsigned short)(u & 0xffffu)), cws[c], g);
      g = fmaf(bf2f((unsigned short)(u >> 16)), cws[c + 1], g);
    }
    gA[tid] = g + cbp[0];
  }
  __syncthreads();

  // per-node partial msum -> slots
  for (int idx = tid; idx < nn * H; idx += 256) {
    int ni = idx >> 7, c = idx & 127;
    int n = nA + ni;
    int o0 = csr_off[n], o1 = csr_off[n + 1];
    int lo = max(o0, P0), hi = min(o1, P1);
    float sum = 0.f;
    for (int pos = lo; pos < hi; ++pos) sum += bf2f(t1s[pos - P0][c]);
    if (o0 >= P0) {
      msA[n * H + c] = sum;
      if (o1 <= P1) msB[n * H + c] = 0.0f;
    } else {
      msB[n * H + c] = sum;
    }
  }
  // per-node partial cu -> slots
  for (int idx = tid; idx < nn * 3; idx += 256) {
    int ni = idx / 3, comp = idx - ni * 3;
    int n = nA + ni;
    int o0 = csr_off[n], o1 = csr_off[n + 1];
    int lo = max(o0, P0), hi = min(o1, P1);
    float sum = 0.f;
    for (int pos = lo; pos < hi; ++pos)
      sum += gA[pos - P0] * dirA[pos - P0][comp];
    if (o0 >= P0) {
      cuA[n * 3 + comp] = sum;
      if (o1 <= P1) cuB[n * 3 + comp] = 0.0f;
    } else {
      cuB[n * 3 + comp] = sum;
    }
  }
}

// ---------------------------------------------------------------------------
// Node update via MFMA: 16 nodes/block, 4 waves (wave w -> cols [32w,32w+32)).
// ins = cat(h, msum/deg) bf16 -> GEMM1 (K=256, nw1T) -> silu -> GEMM2 (K=128).
// ---------------------------------------------------------------------------
__global__ __launch_bounds__(256) void node_mfma_kernel(
    const float* __restrict__ h, const float* __restrict__ msA,
    const float* __restrict__ msB, const int* __restrict__ degi,
    const float* __restrict__ cuA, const float* __restrict__ cuB,
    const float* __restrict__ p_in, const unsigned short* __restrict__ w1T,
    const float* __restrict__ nb1, const unsigned short* __restrict__ w2T,
    const float* __restrict__ nb2, float* __restrict__ h_out,
    float* __restrict__ p_out) {
  __shared__ unsigned short insb[16][264];
  __shared__ unsigned short hnsb[16][136];
  int tid = threadIdx.x;
  int n0 = blockIdx.x * 16;
  for (int idx = tid; idx < 16 * H; idx += 256) {
    int n = idx >> 7, c = idx & 127;
    int gn = n0 + n;
    float hv = h[gn * H + c];
    int dg = degi[gn];
    float ms = 0.f;
    if (dg > 0) ms = (msA[gn * H + c] + msB[gn * H + c]) / (float)dg;
    insb[n][c] = f2bf(hv);
    insb[n][H + c] = f2bf(ms);
  }
  __syncthreads();
  int w = tid >> 6, lane = tid & 63, fr = lane & 15, kg = lane >> 4;
  f32x4 acc[2];
  acc[0] = (f32x4){0.f, 0.f, 0.f, 0.f};
  acc[1] = (f32x4){0.f, 0.f, 0.f, 0.f};
#pragma unroll
  for (int ks = 0; ks < 8; ++ks) {
    int k = ks * 32 + kg * 8;
    short8 a = *(const short8*)&insb[fr][k];
#pragma unroll
    for (int nt = 0; nt < 2; ++nt) {
      int col = w * 32 + nt * 16 + fr;
      short8 b = *(const short8*)&w1T[col * 256 + k];
      acc[nt] = __builtin_amdgcn_mfma_f32_16x16x32_bf16(a, b, acc[nt], 0, 0, 0);
    }
  }
#pragma unroll
  for (int nt = 0; nt < 2; ++nt) {
    int col = w * 32 + nt * 16 + fr;
    float b1 = nb1[col];
#pragma unroll
    for (int r = 0; r < 4; ++r) {
      int row = kg * 4 + r;
      hnsb[row][col] = f2bf(silu(acc[nt][r] + b1));
    }
  }
  __syncthreads();
  f32x4 acc2[2];
  acc2[0] = (f32x4){0.f, 0.f, 0.f, 0.f};
  acc2[1] = (f32x4){0.f, 0.f, 0.f, 0.f};
#pragma unroll
  for (int ks = 0; ks < 4; ++ks) {
    int k = ks * 32 + kg * 8;
    short8 a = *(const short8*)&hnsb[fr][k];
#pragma unroll
    for (int nt = 0; nt < 2; ++nt) {
      int col = w * 32 + nt * 16 + fr;
      short8 b = *(const short8*)&w2T[col * H + k];
      acc2[nt] = __builtin_amdgcn_mfma_f32_16x16x32_bf16(a, b, acc2[nt], 0, 0, 0);
    }
  }
#pragma unroll
  for (int nt = 0; nt < 2; ++nt) {
    int col = w * 32 + nt * 16 + fr;
    float b2 = nb2[col];
#pragma unroll
    for (int r = 0; r < 4; ++r) {
      int row = kg * 4 + r;
      h_out[(n0 + row) * H + col] = acc2[nt][r] + b2;
    }
  }
  if (tid < 48) {
    int nl = tid / 3, comp = tid - nl * 3;
    int gn = n0 + nl;
    int dg = degi[gn];
    float add = 0.0f;
    if (dg > 0)
      add = (cuA[gn * 3 + comp] + cuB[gn * 3 + comp]) / (float)dg;
    p_out[gn * 3 + comp] = p_in[gn * 3 + comp] + add;
  }
}

// ---------------------------------------------------------------------------
// Output head
// ---------------------------------------------------------------------------
__global__ __launch_bounds__(256) void out_kernel(
    const float* __restrict__ h, const float* __restrict__ p,
    const float* __restrict__ ecw, const float* __restrict__ ecb,
    const float* __restrict__ efw, const float* __restrict__ efb,
    float* __restrict__ out) {
  __shared__ float hs[32][H];
  int tid = threadIdx.x, n0 = blockIdx.x * 32;
  for (int idx = tid; idx < 32 * H; idx += 256) {
    int n = idx >> 7, c = idx & 127;
    int gn = n0 + n;
    hs[n][c] = (gn < N_NODES) ? h[gn * H + c] : 0.0f;
  }
  __syncthreads();
  for (int f = tid; f < 32 * 70; f += 256) {
    int nl = f / 70, j = f % 70;
    int gn = n0 + nl;
    if (gn >= N_NODES) continue;
    float v;
    if (j < 3) {
      v = ecb[j];
      for (int c = 0; c < H; ++c) v = fmaf(hs[nl][c], ecw[c * 3 + j], v);
    } else if (j < 67) {
      int jj = j - 3;
      v = efb[jj];
      for (int c = 0; c < H; ++c) v = fmaf(hs[nl][c], efw[c * ND + jj], v);
    } else {
      v = p[gn * 3 + (j - 67)];
    }
    out[gn * 70 + j] = v;
  }
}

// ---------------------------------------------------------------------------
extern "C" void kernel_launch(void* const* d_in, const int* in_sizes, int n_in,
                              void* d_out, int out_size, void* d_ws, size_t ws_size,
                              hipStream_t stream) {
  const float* x = (const float*)d_in[0];
  const float* pos = (const float*)d_in[1];
  const float* t = (const float*)d_in[2];
  const float* s = (const float*)d_in[3];
  const float* pw = (const float*)d_in[4];
  const float* pb = (const float*)d_in[5];
  const float* ew1 = (const float*)d_in[6];
  const float* eb1 = (const float*)d_in[7];
  const float* ew2 = (const float*)d_in[8];
  const float* eb2 = (const float*)d_in[9];
  const float* nw1 = (const float*)d_in[10];
  const float* nb1 = (const float*)d_in[11];
  const float* nw2 = (const float*)d_in[12];
  const float* nb2 = (const float*)d_in[13];
  const float* cw = (const float*)d_in[14];
  const float* cb = (const float*)d_in[15];
  const float* ecw = (const float*)d_in[16];
  const float* ecb = (const float*)d_in[17];
  const float* efw = (const float*)d_in[18];
  const float* efb = (const float*)d_in[19];

  char* wp = (char*)d_ws;
  auto alloc = [&](size_t bytes) {
    char* r = wp;
    wp += (bytes + 255) & ~(size_t)255;
    return r;
  };
  float* h0 = (float*)alloc((size_t)N_NODES * H * 4);
  float* h1 = (float*)alloc((size_t)N_NODES * H * 4);
  float* Abuf = (float*)alloc((size_t)N_NODES * H * 4);
  float* Bbuf = (float*)alloc((size_t)N_NODES * H * 4);
  float* msAb = (float*)alloc((size_t)N_NODES * H * 4);
  float* msBb = (float*)alloc((size_t)N_NODES * H * 4);
  float* cuAb = (float*)alloc((size_t)N_NODES * 3 * 4);
  float* cuBb = (float*)alloc((size_t)N_NODES * 3 * 4);
  float* p0 = (float*)alloc((size_t)N_NODES * 3 * 4);
  float* p1 = (float*)alloc((size_t)N_NODES * 3 * 4);
  int* degi = (int*)alloc((size_t)N_NODES * 4);
  int* nbr = (int*)alloc((size_t)E_EDGES * 4);
  int* off = (int*)alloc((size_t)(N_NODES + 1) * 4);
  int* cursor = (int*)alloc((size_t)N_NODES * 4);
  int* eid = (int*)alloc((size_t)E_EDGES * 4);
  int* dstof = (int*)alloc((size_t)E_EDGES * 4);
  unsigned short* w2Tb = (unsigned short*)alloc((size_t)LAYERS * H * H * 2);
  unsigned short* nw1Tb = (unsigned short*)alloc((size_t)LAYERS * 2 * H * H * 2);
  unsigned short* nw2Tb = (unsigned short*)alloc((size_t)LAYERS * H * H * 2);

  // pos4 aliases msAb (first written by edge_mfma, after KNN is done)
  float4* pos4 = (float4*)msAb;

  hipMemsetAsync(degi, 0, (size_t)N_NODES * 4, stream);
  wcvt_kernel<<<1024, 256, 0, stream>>>(ew2, nw1, nw2, w2Tb, nw1Tb, nw2Tb);
  pos4_kernel<<<(N_NODES + 255) / 256, 256, 0, stream>>>(pos, pos4);
  knn_kernel<<<N_NODES / 4, 256, 0, stream>>>(pos4, nbr);
  deg_count_kernel<<<(E_EDGES + 255) / 256, 256, 0, stream>>>(nbr, degi);
  scan_kernel<<<1, 1024, 0, stream>>>(degi, off, cursor);
  scatter_kernel<<<(E_EDGES + 255) / 256, 256, 0, stream>>>(nbr, cursor, eid, dstof);
  sort_kernel<<<(N_NODES + 255) / 256, 256, 0, stream>>>(off, eid);
  hipMemcpyAsync(p0, pos, (size_t)N_NODES * 3 * 4, hipMemcpyDeviceToDevice, stream);
  proj_kernel<<<N_NODES / 2, 256, 0, stream>>>(x, s, t, pw, pb, h0);

  float* hc = h0;
  float* hn = h1;
  float* pc = p0;
  float* pn = p1;
  for (int l = 0; l < LAYERS; ++l) {
    const float* ew1l = ew1 + (size_t)l * 257 * H;
    ab_kernel<<<N_NODES / 16, 256, 0, stream>>>(hc, ew1l, eb1 + l * H, Abuf, Bbuf);
    edge_mfma_kernel<<<E_EDGES / TILE_E, 256, 0, stream>>>(
        Abuf, Bbuf, pc, s, off, eid, dstof, ew1l + 256 * H,
        w2Tb + (size_t)l * H * H, eb2 + l * H, cw + l * H, cb + l,
        msAb, msBb, cuAb, cuBb);
    node_mfma_kernel<<<N_NODES / 16, 256, 0, stream>>>(
        hc, msAb, msBb, degi, cuAb, cuBb, pc, nw1Tb + (size_t)l * 2 * H * H,
        nb1 + l * H, nw2Tb + (size_t)l * H * H, nb2 + l * H, hn, pn);
    float* tmp = hc; hc = hn; hn = tmp;
    tmp = pc; pc = pn; pn = tmp;
  }
  out_kernel<<<(N_NODES + 31) / 32, 256, 0, stream>>>(hc, pc, ecw, ecb, efw, efb,
                                                      (float*)d_out);
}